// Round 7
// baseline (1060.128 us; speedup 1.0000x reference)
//
#include <hip/hip_runtime.h>
#include <hip/hip_bf16.h>
#include <cstring>

using bf16 = __hip_bfloat16;

// ---- problem constants ----
constexpr int NH    = 128;    // hidden
constexpr int G4    = 512;    // 4*H gates
constexpr int TSEQ  = 200;
constexpr int BBATCH= 32;
constexpr int NTGT  = 8;

// ---- subgraph caps (Poisson means: |L1|~64, |S1|~72, |L2|~580, |S2|~650) ----
constexpr int LCAP1 = 1024;
constexpr int S1CAP = LCAP1 + NTGT;
constexpr int LCAP2 = 8192;
constexpr int S2CAP = LCAP2 + S1CAP;

// ---- workspace layout (bytes) ----
constexpr size_t algn(size_t x) { return (x + 255) & ~size_t(255); }
constexpr size_t OFF_GX1  = 0;                                            // 6400*512 f32
constexpr size_t OFF_GX2  = algn(OFF_GX1  + 6400ull * G4 * 4);            // 32*512 f32
constexpr size_t OFF_DEG  = algn(OFF_GX2  + 32ull * G4 * 4);              // N i32
constexpr size_t OFF_DINV = algn(OFF_DEG  + 100000ull * 4);               // N f32
constexpr size_t OFF_SL1  = algn(OFF_DINV + 100000ull * 4);               // N i32
constexpr size_t OFF_SL2  = algn(OFF_SL1  + 100000ull * 4);               // N i32
constexpr size_t OFF_CNT  = algn(OFF_SL2  + 100000ull * 4);               // 16 i32
constexpr size_t OFF_L1   = algn(OFF_CNT  + 64);                          // LCAP1 int2
constexpr size_t OFF_S1   = algn(OFF_L1   + (size_t)LCAP1 * 8);           // S1CAP i32
constexpr size_t OFF_L2   = algn(OFF_S1   + (size_t)S1CAP * 4);           // LCAP2 int2
constexpr size_t OFF_S2   = algn(OFF_L2   + (size_t)LCAP2 * 8);           // S2CAP i32
constexpr size_t OFF_XW1  = algn(OFF_S2   + (size_t)S2CAP * 4);           // S2CAP*128 f32
constexpr size_t OFF_H1   = algn(OFF_XW1  + (size_t)S2CAP * NH * 4);      // S1CAP*128 f32
constexpr size_t OFF_XW2  = algn(OFF_H1   + (size_t)S1CAP * NH * 4);      // S1CAP*128 f32
constexpr size_t OFF_DVEC = algn(OFF_XW2  + (size_t)S1CAP * NH * 4);      // 1152 f32
constexpr size_t OFF_H1F  = algn(OFF_DVEC + 1152ull * 4);                 // 32*128 f32
constexpr size_t WS_NEEDED = OFF_H1F + 32ull * NH * 4;

// edge_index may be staged as int64 (reference dtype) or int32. If int64,
// odd int32 words are the (all-zero) high halves. cnt[15] = sniffed flag.
__device__ __forceinline__ int edge_at(const int* ei, int E, int is64, int row, int e) {
    return is64 ? ei[(((size_t)row * E) + e) * 2] : ei[((size_t)row * E) + e];
}

// ============================ diagnostic canary ============================
// Dual-dtype store: pattern (b<<16)|b reads as value v under BOTH a bf16
// readback (low 16 bits) and an fp32 readback (top 16 bits dominate).
__global__ void k_canary(unsigned int* out, unsigned int bits) {
    if (threadIdx.x == 0) out[0] = bits;
}

// ============================ GCN subgraph build ============================

__global__ void k_init(const int* ei, int* deg, int* slot1, int* slot2, int* cnt, int n) {
    int i = blockIdx.x * 256 + threadIdx.x;
    if (i < 14) cnt[i] = 0;
    if (i == 15) cnt[15] = (ei[1] == 0 && ei[3] == 0 && ei[5] == 0 && ei[7] == 0) ? 1 : 0;
    for (; i < n; i += gridDim.x * 256) { deg[i] = 0; slot1[i] = -1; slot2[i] = -1; }
}

__global__ void k_deg_l1(const int* ei, int E, int* deg, int2* l1, int* cnt) {
    int is64 = cnt[15];
    for (int e = blockIdx.x * 256 + threadIdx.x; e < E; e += gridDim.x * 256) {
        int d = edge_at(ei, E, is64, 1, e);
        if ((unsigned)d < 100000u) atomicAdd(&deg[d], 1);
        if (d <= 7000 && d >= 0 && d % 1000 == 0) {          // d in TARGET
            int s = edge_at(ei, E, is64, 0, e);
            int idx = atomicAdd(&cnt[0], 1);
            if (idx < LCAP1) l1[idx] = make_int2(s, d);
        }
    }
}

__global__ void k_dinv(const int* deg, float* dinv, int n) {
    for (int i = blockIdx.x * 256 + threadIdx.x; i < n; i += gridDim.x * 256)
        dinv[i] = rsqrtf((float)deg[i] + 1.0f);
}

__global__ void k_s1(const int2* l1, int* cnt, int* slot1, int* s1list) {
    int m = min(cnt[0], LCAP1);
    for (int i = threadIdx.x; i < NTGT + m; i += blockDim.x) {
        int v = (i < NTGT) ? i * 1000 : l1[i - NTGT].x;
        if ((unsigned)v >= 100000u) continue;
        int old = atomicCAS(&slot1[v], -1, -2);
        if (old == -1) {
            int idx = atomicAdd(&cnt[1], 1);
            if (idx < S1CAP) { s1list[idx] = v; atomicExch(&slot1[v], idx); }
        }
    }
}

__global__ void k_s2self(const int* s1list, int* cnt, int* slot2, int* s2list) {
    int nS1 = min(cnt[1], S1CAP);
    for (int i = blockIdx.x * 256 + threadIdx.x; i < nS1; i += gridDim.x * 256) {
        int v = s1list[i];
        int old = atomicCAS(&slot2[v], -1, -2);
        if (old == -1) {
            int idx = atomicAdd(&cnt[2], 1);
            if (idx < S2CAP) { s2list[idx] = v; atomicExch(&slot2[v], idx); }
        }
    }
}

__global__ void k_l2(const int* ei, int E, const int* slot1,
                     int2* l2, int* cnt, int* slot2, int* s2list) {
    int is64 = cnt[15];
    for (int e = blockIdx.x * 256 + threadIdx.x; e < E; e += gridDim.x * 256) {
        int d = edge_at(ei, E, is64, 1, e);
        if ((unsigned)d >= 100000u) continue;
        if (slot1[d] >= 0) {
            int s = edge_at(ei, E, is64, 0, e);
            if ((unsigned)s >= 100000u) continue;
            int idx = atomicAdd(&cnt[3], 1);
            if (idx < LCAP2) l2[idx] = make_int2(s, d);
            int old = atomicCAS(&slot2[s], -1, -2);
            if (old == -1) {
                int j = atomicAdd(&cnt[2], 1);
                if (j < S2CAP) { s2list[j] = s; atomicExch(&slot2[s], j); }
            }
        }
    }
}

// ============================ GCN compute (fp32 inputs) ============================

__global__ void k_xw1(const float* x, const float* W, const int* s2list, const int* cnt, float* xw1) {
    int i = blockIdx.x;
    if (i >= min(cnt[2], S2CAP)) return;
    int node = s2list[i];
    __shared__ float xs[NH];
    int c = threadIdx.x;
    xs[c] = x[(size_t)node * NH + c];
    __syncthreads();
    float acc = 0.f;
    #pragma unroll 8
    for (int k = 0; k < NH; k++) acc += xs[k] * W[(size_t)k * NH + c];
    xw1[(size_t)i * NH + c] = acc;
}

__global__ void k_h1init(const float* xw1, const int* s1list, const int* cnt,
                         const int* slot2, const float* dinv, float* h1) {
    int i = blockIdx.x;
    if (i >= min(cnt[1], S1CAP)) return;
    int node = s1list[i];
    int s2 = slot2[node];
    if (s2 < 0 || s2 >= S2CAP) s2 = 0;
    float v = dinv[node];
    h1[i * NH + threadIdx.x] = xw1[(size_t)s2 * NH + threadIdx.x] * v * v;
}

__global__ void k_h1scat(const float* xw1, const int2* l2, const int* cnt,
                         const int* slot1, const int* slot2, const float* dinv, float* h1) {
    int e = blockIdx.x;
    if (e >= min(cnt[3], LCAP2)) return;
    int2 sd = l2[e];
    int t1 = slot1[sd.y], s2 = slot2[sd.x];
    if (t1 < 0 || t1 >= S1CAP || s2 < 0 || s2 >= S2CAP) return;
    float w = dinv[sd.x] * dinv[sd.y];
    atomicAdd(&h1[t1 * NH + threadIdx.x],
              xw1[(size_t)s2 * NH + threadIdx.x] * w);
}

// fused: relu(h1 + b1) then @ W2
__global__ void k_xw2(const float* h1, const float* W, const float* b1, const int* cnt, float* xw2) {
    int i = blockIdx.x;
    if (i >= min(cnt[1], S1CAP)) return;
    __shared__ float xs[NH];
    int c = threadIdx.x;
    xs[c] = fmaxf(h1[i * NH + c] + b1[c], 0.f);
    __syncthreads();
    float acc = 0.f;
    #pragma unroll 8
    for (int k = 0; k < NH; k++) acc += xs[k] * W[(size_t)k * NH + c];
    xw2[(size_t)i * NH + c] = acc;
}

__global__ void k_gout(const float* xw2, const int2* l1, const int* cnt,
                       const int* slot1, const float* dinv, const float* b2, float* dvec) {
    int t = blockIdx.x;             // 0..7
    int tgt = t * 1000;
    int c = threadIdx.x;
    float vt = dinv[tgt];
    int st = slot1[tgt]; if (st < 0 || st >= S1CAP) st = 0;
    float acc = xw2[(size_t)st * NH + c] * vt * vt;
    int m = min(cnt[0], LCAP1);
    for (int e = 0; e < m; e++) {
        int2 sd = l1[e];
        if (sd.y == tgt) {
            int ss = slot1[sd.x];
            if (ss >= 0 && ss < S1CAP)
                acc += xw2[(size_t)ss * NH + c] * dinv[sd.x] * vt;
        }
    }
    acc += b2[c];
    dvec[t * NH + c] = fmaxf(acc, 0.f);
}

// ============================ LSTM (fp32 inputs) ============================

// gx1[t][b][g] = data0[b][t][:] . Wih1[g][:] + bih1[g] + bhh1[g]; 256 thr, 2 gates.
__global__ void k_gx1(const float* data0, const float* Wih,
                      const float* bih, const float* bhh, float* gx) {
    __shared__ float xs[32][64];
    int tid = threadIdx.x;
    int g0 = tid, g1 = tid + 256;
    int r0 = blockIdx.x * 32;                       // rows r = t*32 + b
    for (int i = tid; i < 32 * 64; i += 256) {
        int rr = i >> 6, k = i & 63;
        int r = r0 + rr, t = r >> 5, b = r & 31;
        xs[rr][k] = data0[((size_t)b * TSEQ + t) * 64 + k];
    }
    float w0[64], w1[64];
    #pragma unroll
    for (int k = 0; k < 64; k++) { w0[k] = Wih[(size_t)g0 * 64 + k]; w1[k] = Wih[(size_t)g1 * 64 + k]; }
    float bias0 = bih[g0] + bhh[g0];
    float bias1 = bih[g1] + bhh[g1];
    __syncthreads();
    for (int rr = 0; rr < 32; rr++) {
        float a0 = bias0, a1 = bias1;
        #pragma unroll
        for (int k = 0; k < 64; k++) { a0 += w0[k] * xs[rr][k]; a1 += w1[k] * xs[rr][k]; }
        gx[(size_t)(r0 + rr) * G4 + g0] = a0;
        gx[(size_t)(r0 + rr) * G4 + g1] = a1;
    }
}

// gx2[t][g] = h1f[t][:] . Wih2[g][:] + biases; 256 thr, 2 gates.
__global__ void k_gx2(const float* h1f, const float* Wih,
                      const float* bih, const float* bhh, float* gx) {
    int t = blockIdx.x;
    __shared__ float xs[NH];
    int tid = threadIdx.x;
    int g0 = tid, g1 = tid + 256;
    if (tid < NH) xs[tid] = h1f[t * NH + tid];
    __syncthreads();
    float a0 = bih[g0] + bhh[g0];
    float a1 = bih[g1] + bhh[g1];
    #pragma unroll 4
    for (int k = 0; k < NH; k++) {
        a0 += Wih[(size_t)g0 * NH + k] * xs[k];
        a1 += Wih[(size_t)g1 * NH + k] * xs[k];
    }
    gx[(size_t)t * G4 + g0] = a0;
    gx[(size_t)t * G4 + g1] = a1;
}

// recurrence: one block per batch element, 256 threads, 2 gates/thread.
template<int T, int NB>
__global__ __launch_bounds__(256, 1) void k_lstm(const float* gx, const float* Whh, float* hfinal) {
    int b = blockIdx.x;
    int t0 = threadIdx.x;
    int g0 = t0, g1 = t0 + 256;
    __shared__ __align__(16) float hs[NH];
    __shared__ float gs[G4];
    float w0[NH], w1[NH];
    #pragma unroll
    for (int k = 0; k < NH; k++) { w0[k] = Whh[(size_t)g0 * NH + k]; w1[k] = Whh[(size_t)g1 * NH + k]; }
    if (t0 < NH) hs[t0] = 0.f;
    float c = 0.f;
    float nx0 = gx[((size_t)0 * NB + b) * G4 + g0];
    float nx1 = gx[((size_t)0 * NB + b) * G4 + g1];
    __syncthreads();
    for (int t = 0; t < T; t++) {
        float a0 = nx0, a1 = nx1;
        int tn = (t + 1 < T) ? (t + 1) : t;
        nx0 = gx[((size_t)tn * NB + b) * G4 + g0];          // prefetch next step
        nx1 = gx[((size_t)tn * NB + b) * G4 + g1];
        float p0 = 0.f, q0 = 0.f, p1 = 0.f, q1 = 0.f;
        #pragma unroll
        for (int k = 0; k < NH; k += 8) {
            float4 h4 = *(const float4*)&hs[k];
            float4 h5 = *(const float4*)&hs[k + 4];
            p0 += w0[k]   * h4.x + w0[k+1] * h4.y + w0[k+2] * h4.z + w0[k+3] * h4.w;
            q0 += w0[k+4] * h5.x + w0[k+5] * h5.y + w0[k+6] * h5.z + w0[k+7] * h5.w;
            p1 += w1[k]   * h4.x + w1[k+1] * h4.y + w1[k+2] * h4.z + w1[k+3] * h4.w;
            q1 += w1[k+4] * h5.x + w1[k+5] * h5.y + w1[k+6] * h5.z + w1[k+7] * h5.w;
        }
        gs[g0] = a0 + p0 + q0;
        gs[g1] = a1 + p1 + q1;
        __syncthreads();
        if (t0 < NH) {
            int j = t0;
            float gi = gs[j], gf = gs[NH + j], gg = gs[2 * NH + j], go = gs[3 * NH + j];
            float si = 1.f / (1.f + __expf(-gi));
            float sf = 1.f / (1.f + __expf(-gf));
            float so = 1.f / (1.f + __expf(-go));
            c = sf * c + si * tanhf(gg);
            hs[j] = so * tanhf(c);
        }
        __syncthreads();
    }
    if (t0 < NH) hfinal[(size_t)b * NH + t0] = hs[t0];
}

// ============================ head ============================
// 256 threads; dual-dtype final store (valid under bf16 and fp32 readback).
__global__ void k_head(const float* dvec, const float* m1w, const float* m1b,
                       const float* m2w, const float* m2b, unsigned int* out) {
    __shared__ float ds[1152];
    __shared__ float wr[4];
    int j = threadIdx.x;
    for (int i = j; i < 1152; i += 256) ds[i] = dvec[i];
    __syncthreads();
    float sum = 0.f;
    for (int col = j; col < 576; col += 256) {
        float t1 = m1b[col];
        #pragma unroll 4
        for (int i = 0; i < 1152; i++) t1 += ds[i] * m1w[(size_t)i * 576 + col];
        sum += t1 * m2w[col];
    }
    #pragma unroll
    for (int off = 32; off > 0; off >>= 1) sum += __shfl_down(sum, off, 64);
    if ((j & 63) == 0) wr[j >> 6] = sum;
    __syncthreads();
    if (j == 0) {
        float s = wr[0] + wr[1] + wr[2] + wr[3] + m2b[0];
        bf16 hb = __float2bfloat16(s);
        unsigned short u;
        memcpy(&u, &hb, 2);
        out[0] = ((unsigned int)u << 16) | u;
    }
}

// ============================ launcher ============================

extern "C" void kernel_launch(void* const* d_in, const int* in_sizes, int n_in,
                              void* d_out, int out_size, void* d_ws, size_t ws_size,
                              hipStream_t stream) {
    const float* data0 = (const float*)d_in[0];
    const float* data1 = (const float*)d_in[1];
    const int*   ei    = (const int*)d_in[2];
    const float* W1    = (const float*)d_in[3];
    const float* b1    = (const float*)d_in[4];
    const float* W2    = (const float*)d_in[5];
    const float* b2    = (const float*)d_in[6];
    const float* Wih1  = (const float*)d_in[7];
    const float* Whh1  = (const float*)d_in[8];
    const float* bih1  = (const float*)d_in[9];
    const float* bhh1  = (const float*)d_in[10];
    const float* Wih2  = (const float*)d_in[11];
    const float* Whh2  = (const float*)d_in[12];
    const float* bih2  = (const float*)d_in[13];
    const float* bhh2  = (const float*)d_in[14];
    const float* m1w   = (const float*)d_in[15];
    const float* m1b   = (const float*)d_in[16];
    const float* m2w   = (const float*)d_in[17];
    const float* m2b   = (const float*)d_in[18];

    const int n = in_sizes[1] / NH;       // 100000
    const int E = in_sizes[2] / 2;        // 800000 (elements; int width sniffed on device)

    char* ws = (char*)d_ws;
    float* gx1   = (float*)(ws + OFF_GX1);
    float* gx2   = (float*)(ws + OFF_GX2);
    int*   deg   = (int*)  (ws + OFF_DEG);
    float* dinv  = (float*)(ws + OFF_DINV);
    int*   slot1 = (int*)  (ws + OFF_SL1);
    int*   slot2 = (int*)  (ws + OFF_SL2);
    int*   cnt   = (int*)  (ws + OFF_CNT);
    int2*  l1    = (int2*) (ws + OFF_L1);
    int*   s1l   = (int*)  (ws + OFF_S1);
    int2*  l2    = (int2*) (ws + OFF_L2);
    int*   s2l   = (int*)  (ws + OFF_S2);
    float* xw1   = (float*)(ws + OFF_XW1);
    float* h1    = (float*)(ws + OFF_H1);
    float* xw2   = (float*)(ws + OFF_XW2);
    float* dvec  = (float*)(ws + OFF_DVEC);
    float* h1f   = (float*)(ws + OFF_H1F);

    // diagnostic canary: v = 1 + 1*(ws too small) + 2*(n_in mismatch);
    // dual-dtype pattern, overwritten by k_head with the real answer.
    float v = 1.0f + (ws_size < WS_NEEDED ? 1.0f : 0.0f) + (n_in != 19 ? 2.0f : 0.0f);
    unsigned int fb; memcpy(&fb, &v, 4);
    unsigned int hi = fb >> 16;
    unsigned int canary_bits = (hi << 16) | hi;
    k_canary <<<1, 64, 0, stream>>>((unsigned int*)d_out, canary_bits);

    int nb = (n + 255) / 256;
    int eb = (E + 255) / 256;

    // subgraph build
    k_init   <<<nb, 256, 0, stream>>>(ei, deg, slot1, slot2, cnt, n);
    k_deg_l1 <<<eb, 256, 0, stream>>>(ei, E, deg, l1, cnt);
    k_dinv   <<<nb, 256, 0, stream>>>(deg, dinv, n);
    k_s1     <<<1, 256, 0, stream>>>(l1, cnt, slot1, s1l);
    k_s2self <<<8, 256, 0, stream>>>(s1l, cnt, slot2, s2l);
    k_l2     <<<eb, 256, 0, stream>>>(ei, E, slot1, l2, cnt, slot2, s2l);
    // GCN compute on active subgraph
    k_xw1    <<<S2CAP, NH, 0, stream>>>(data1, W1, s2l, cnt, xw1);
    k_h1init <<<S1CAP, NH, 0, stream>>>(xw1, s1l, cnt, slot2, dinv, h1);
    k_h1scat <<<LCAP2, NH, 0, stream>>>(xw1, l2, cnt, slot1, slot2, dinv, h1);
    k_xw2    <<<S1CAP, NH, 0, stream>>>(h1, W2, b1, cnt, xw2);
    k_gout   <<<NTGT, NH, 0, stream>>>(xw2, l1, cnt, slot1, dinv, b2, dvec);
    // LSTM path
    k_gx1    <<<TSEQ * BBATCH / 32, 256, 0, stream>>>(data0, Wih1, bih1, bhh1, gx1);
    k_lstm<TSEQ, BBATCH><<<BBATCH, 256, 0, stream>>>(gx1, Whh1, h1f);
    k_gx2    <<<BBATCH, 256, 0, stream>>>(h1f, Wih2, bih2, bhh2, gx2);
    k_lstm<BBATCH, 1>  <<<1, 256, 0, stream>>>(gx2, Whh2, dvec + 1024);
    // head (overwrites canary with the real answer)
    k_head   <<<1, 256, 0, stream>>>(dvec, m1w, m1b, m2w, m2b, (unsigned int*)d_out);
    (void)out_size;
}

// Round 8
// 652.868 us; speedup vs baseline: 1.6238x; 1.6238x over previous
//
#include <hip/hip_runtime.h>
#include <hip/hip_bf16.h>
#include <cstring>

using bf16 = __hip_bfloat16;
typedef _Float16 h2v __attribute__((ext_vector_type(2)));

#if __has_builtin(__builtin_amdgcn_fdot2)
__device__ __forceinline__ float FDOT2(h2v a, h2v b, float c) {
    return __builtin_amdgcn_fdot2(a, b, c, false);
}
#else
__device__ __forceinline__ float FDOT2(h2v a, h2v b, float c) {
    return c + (float)a.x * (float)b.x + (float)a.y * (float)b.y;
}
#endif

// ---- problem constants ----
constexpr int NH    = 128;    // hidden
constexpr int G4    = 512;    // 4*H gates
constexpr int TSEQ  = 200;
constexpr int BBATCH= 32;
constexpr int NTGT  = 8;

// ---- subgraph caps (Poisson means: |L1|~64, |S1|~72, |L2|~580, |S2|~650) ----
constexpr int LCAP1 = 1024;
constexpr int S1CAP = LCAP1 + NTGT;
constexpr int LCAP2 = 8192;
constexpr int S2CAP = LCAP2 + S1CAP;

// ---- workspace layout (bytes) ----
constexpr size_t algn(size_t x) { return (x + 255) & ~size_t(255); }
constexpr size_t OFF_GX1  = 0;                                            // 6400*512 f32
constexpr size_t OFF_GX2  = algn(OFF_GX1  + 6400ull * G4 * 4);            // 32*512 f32
constexpr size_t OFF_DEG  = algn(OFF_GX2  + 32ull * G4 * 4);              // N i32
constexpr size_t OFF_DINV = algn(OFF_DEG  + 100000ull * 4);               // N f32
constexpr size_t OFF_SL1  = algn(OFF_DINV + 100000ull * 4);               // N i32
constexpr size_t OFF_SL2  = algn(OFF_SL1  + 100000ull * 4);               // N i32
constexpr size_t OFF_CNT  = algn(OFF_SL2  + 100000ull * 4);               // 16 i32
constexpr size_t OFF_L1   = algn(OFF_CNT  + 64);                          // LCAP1 int2
constexpr size_t OFF_S1   = algn(OFF_L1   + (size_t)LCAP1 * 8);           // S1CAP i32
constexpr size_t OFF_L2   = algn(OFF_S1   + (size_t)S1CAP * 4);           // LCAP2 int2
constexpr size_t OFF_S2   = algn(OFF_L2   + (size_t)LCAP2 * 8);           // S2CAP i32
constexpr size_t OFF_XW1  = algn(OFF_S2   + (size_t)S2CAP * 4);           // S2CAP*128 f32
constexpr size_t OFF_H1   = algn(OFF_XW1  + (size_t)S2CAP * NH * 4);      // S1CAP*128 f32
constexpr size_t OFF_XW2  = algn(OFF_H1   + (size_t)S1CAP * NH * 4);      // S1CAP*128 f32
constexpr size_t OFF_DVEC = algn(OFF_XW2  + (size_t)S1CAP * NH * 4);      // 1152 f32
constexpr size_t OFF_H1F  = algn(OFF_DVEC + 1152ull * 4);                 // 32*128 f32
constexpr size_t OFF_CACC = algn(OFF_H1F  + 32ull * NH * 4);              // 576 f32
constexpr size_t WS_NEEDED = OFF_CACC + 576ull * 4;

// edge_index may be staged as int64 (reference dtype) or int32. If int64,
// odd int32 words are the (all-zero) high halves. cnt[15] = sniffed flag.
__device__ __forceinline__ int edge_at(const int* ei, int E, int is64, int row, int e) {
    return is64 ? ei[(((size_t)row * E) + e) * 2] : ei[((size_t)row * E) + e];
}

// ============================ diagnostic canary ============================
__global__ void k_canary(unsigned int* out, unsigned int bits) {
    if (threadIdx.x == 0) out[0] = bits;
}

// ============================ GCN subgraph build ============================

__global__ void k_init(const int* ei, int* deg, int* slot1, int* slot2, int* cnt,
                       float* colacc, int n) {
    int i = blockIdx.x * 256 + threadIdx.x;
    if (i < 14) cnt[i] = 0;
    if (i == 15) cnt[15] = (ei[1] == 0 && ei[3] == 0 && ei[5] == 0 && ei[7] == 0) ? 1 : 0;
    if (i < 576) colacc[i] = 0.f;
    for (; i < n; i += gridDim.x * 256) { deg[i] = 0; slot1[i] = -1; slot2[i] = -1; }
}

__global__ void k_deg_l1(const int* ei, int E, int* deg, int2* l1, int* cnt) {
    int is64 = cnt[15];
    for (int e = blockIdx.x * 256 + threadIdx.x; e < E; e += gridDim.x * 256) {
        int d = edge_at(ei, E, is64, 1, e);
        if ((unsigned)d < 100000u) atomicAdd(&deg[d], 1);
        if (d <= 7000 && d >= 0 && d % 1000 == 0) {          // d in TARGET
            int s = edge_at(ei, E, is64, 0, e);
            int idx = atomicAdd(&cnt[0], 1);
            if (idx < LCAP1) l1[idx] = make_int2(s, d);
        }
    }
}

__global__ void k_dinv(const int* deg, float* dinv, int n) {
    for (int i = blockIdx.x * 256 + threadIdx.x; i < n; i += gridDim.x * 256)
        dinv[i] = rsqrtf((float)deg[i] + 1.0f);
}

__global__ void k_s1(const int2* l1, int* cnt, int* slot1, int* s1list) {
    int m = min(cnt[0], LCAP1);
    for (int i = threadIdx.x; i < NTGT + m; i += blockDim.x) {
        int v = (i < NTGT) ? i * 1000 : l1[i - NTGT].x;
        if ((unsigned)v >= 100000u) continue;
        int old = atomicCAS(&slot1[v], -1, -2);
        if (old == -1) {
            int idx = atomicAdd(&cnt[1], 1);
            if (idx < S1CAP) { s1list[idx] = v; atomicExch(&slot1[v], idx); }
        }
    }
}

__global__ void k_s2self(const int* s1list, int* cnt, int* slot2, int* s2list) {
    int nS1 = min(cnt[1], S1CAP);
    for (int i = blockIdx.x * 256 + threadIdx.x; i < nS1; i += gridDim.x * 256) {
        int v = s1list[i];
        int old = atomicCAS(&slot2[v], -1, -2);
        if (old == -1) {
            int idx = atomicAdd(&cnt[2], 1);
            if (idx < S2CAP) { s2list[idx] = v; atomicExch(&slot2[v], idx); }
        }
    }
}

__global__ void k_l2(const int* ei, int E, const int* slot1,
                     int2* l2, int* cnt, int* slot2, int* s2list) {
    int is64 = cnt[15];
    for (int e = blockIdx.x * 256 + threadIdx.x; e < E; e += gridDim.x * 256) {
        int d = edge_at(ei, E, is64, 1, e);
        if ((unsigned)d >= 100000u) continue;
        if (slot1[d] >= 0) {
            int s = edge_at(ei, E, is64, 0, e);
            if ((unsigned)s >= 100000u) continue;
            int idx = atomicAdd(&cnt[3], 1);
            if (idx < LCAP2) l2[idx] = make_int2(s, d);
            int old = atomicCAS(&slot2[s], -1, -2);
            if (old == -1) {
                int j = atomicAdd(&cnt[2], 1);
                if (j < S2CAP) { s2list[j] = s; atomicExch(&slot2[s], j); }
            }
        }
    }
}

// ============================ GCN compute (fp32 inputs) ============================

__global__ void k_xw1(const float* x, const float* W, const int* s2list, const int* cnt, float* xw1) {
    int i = blockIdx.x;
    if (i >= min(cnt[2], S2CAP)) return;
    int node = s2list[i];
    __shared__ float xs[NH];
    int c = threadIdx.x;
    xs[c] = x[(size_t)node * NH + c];
    __syncthreads();
    float acc = 0.f;
    #pragma unroll 8
    for (int k = 0; k < NH; k++) acc += xs[k] * W[(size_t)k * NH + c];
    xw1[(size_t)i * NH + c] = acc;
}

__global__ void k_h1init(const float* xw1, const int* s1list, const int* cnt,
                         const int* slot2, const float* dinv, float* h1) {
    int i = blockIdx.x;
    if (i >= min(cnt[1], S1CAP)) return;
    int node = s1list[i];
    int s2 = slot2[node];
    if (s2 < 0 || s2 >= S2CAP) s2 = 0;
    float v = dinv[node];
    h1[i * NH + threadIdx.x] = xw1[(size_t)s2 * NH + threadIdx.x] * v * v;
}

__global__ void k_h1scat(const float* xw1, const int2* l2, const int* cnt,
                         const int* slot1, const int* slot2, const float* dinv, float* h1) {
    int e = blockIdx.x;
    if (e >= min(cnt[3], LCAP2)) return;
    int2 sd = l2[e];
    int t1 = slot1[sd.y], s2 = slot2[sd.x];
    if (t1 < 0 || t1 >= S1CAP || s2 < 0 || s2 >= S2CAP) return;
    float w = dinv[sd.x] * dinv[sd.y];
    atomicAdd(&h1[t1 * NH + threadIdx.x],
              xw1[(size_t)s2 * NH + threadIdx.x] * w);
}

// fused: relu(h1 + b1) then @ W2
__global__ void k_xw2(const float* h1, const float* W, const float* b1, const int* cnt, float* xw2) {
    int i = blockIdx.x;
    if (i >= min(cnt[1], S1CAP)) return;
    __shared__ float xs[NH];
    int c = threadIdx.x;
    xs[c] = fmaxf(h1[i * NH + c] + b1[c], 0.f);
    __syncthreads();
    float acc = 0.f;
    #pragma unroll 8
    for (int k = 0; k < NH; k++) acc += xs[k] * W[(size_t)k * NH + c];
    xw2[(size_t)i * NH + c] = acc;
}

__global__ void k_gout(const float* xw2, const int2* l1, const int* cnt,
                       const int* slot1, const float* dinv, const float* b2, float* dvec) {
    int t = blockIdx.x;             // 0..7
    int tgt = t * 1000;
    int c = threadIdx.x;
    float vt = dinv[tgt];
    int st = slot1[tgt]; if (st < 0 || st >= S1CAP) st = 0;
    float acc = xw2[(size_t)st * NH + c] * vt * vt;
    int m = min(cnt[0], LCAP1);
    for (int e = 0; e < m; e++) {
        int2 sd = l1[e];
        if (sd.y == tgt) {
            int ss = slot1[sd.x];
            if (ss >= 0 && ss < S1CAP)
                acc += xw2[(size_t)ss * NH + c] * dinv[sd.x] * vt;
        }
    }
    acc += b2[c];
    dvec[t * NH + c] = fmaxf(acc, 0.f);
}

// ============================ LSTM (fp32 inputs) ============================

// gx1[t][b][g] = data0[b][t][:] . Wih1[g][:] + bih1[g] + bhh1[g]; 256 thr, 2 gates.
__global__ void k_gx1(const float* data0, const float* Wih,
                      const float* bih, const float* bhh, float* gx) {
    __shared__ float xs[32][64];
    int tid = threadIdx.x;
    int g0 = tid, g1 = tid + 256;
    int r0 = blockIdx.x * 32;                       // rows r = t*32 + b
    for (int i = tid; i < 32 * 64; i += 256) {
        int rr = i >> 6, k = i & 63;
        int r = r0 + rr, t = r >> 5, b = r & 31;
        xs[rr][k] = data0[((size_t)b * TSEQ + t) * 64 + k];
    }
    float w0[64], w1[64];
    #pragma unroll
    for (int k = 0; k < 64; k++) { w0[k] = Wih[(size_t)g0 * 64 + k]; w1[k] = Wih[(size_t)g1 * 64 + k]; }
    float bias0 = bih[g0] + bhh[g0];
    float bias1 = bih[g1] + bhh[g1];
    __syncthreads();
    for (int rr = 0; rr < 32; rr++) {
        float a0 = bias0, a1 = bias1;
        #pragma unroll
        for (int k = 0; k < 64; k++) { a0 += w0[k] * xs[rr][k]; a1 += w1[k] * xs[rr][k]; }
        gx[(size_t)(r0 + rr) * G4 + g0] = a0;
        gx[(size_t)(r0 + rr) * G4 + g1] = a1;
    }
}

// gx2[t][g] = h1f[t][:] . Wih2[g][:] + biases; 256 thr, 2 gates.
__global__ void k_gx2(const float* h1f, const float* Wih,
                      const float* bih, const float* bhh, float* gx) {
    int t = blockIdx.x;
    __shared__ float xs[NH];
    int tid = threadIdx.x;
    int g0 = tid, g1 = tid + 256;
    if (tid < NH) xs[tid] = h1f[t * NH + tid];
    __syncthreads();
    float a0 = bih[g0] + bhh[g0];
    float a1 = bih[g1] + bhh[g1];
    #pragma unroll 4
    for (int k = 0; k < NH; k++) {
        a0 += Wih[(size_t)g0 * NH + k] * xs[k];
        a1 += Wih[(size_t)g1 * NH + k] * xs[k];
    }
    gx[(size_t)t * G4 + g0] = a0;
    gx[(size_t)t * G4 + g1] = a1;
}

// recurrence: 1 block/batch, 256 thr, 2 gates/thread. Weights as fp16 half2
// in VGPRs (64 dwords/gate — avoids the 256-fp32 spill seen at VGPR_Count=148);
// h broadcast as packed fp16 in LDS; fp32 accumulate and fp32 cell math.
template<int T, int NB>
__global__ __launch_bounds__(256, 1) void k_lstm(const float* gx, const float* Whh, float* hfinal) {
    int b = blockIdx.x;
    int t0 = threadIdx.x;
    int g0 = t0, g1 = t0 + 256;
    __shared__ __align__(16) _Float16 h2h[NH];
    __shared__ float gs[G4];
    h2v w0[NH / 2], w1[NH / 2];
    #pragma unroll
    for (int k = 0; k < NH; k += 4) {
        float4 a = *(const float4*)&Whh[(size_t)g0 * NH + k];
        w0[k / 2]     = h2v{(_Float16)a.x, (_Float16)a.y};
        w0[k / 2 + 1] = h2v{(_Float16)a.z, (_Float16)a.w};
        float4 c4 = *(const float4*)&Whh[(size_t)g1 * NH + k];
        w1[k / 2]     = h2v{(_Float16)c4.x, (_Float16)c4.y};
        w1[k / 2 + 1] = h2v{(_Float16)c4.z, (_Float16)c4.w};
    }
    if (t0 < NH) h2h[t0] = (_Float16)0.f;
    float c = 0.f, h = 0.f;
    float nx0 = gx[((size_t)0 * NB + b) * G4 + g0];
    float nx1 = gx[((size_t)0 * NB + b) * G4 + g1];
    __syncthreads();
    const h2v* hv = (const h2v*)h2h;
    for (int t = 0; t < T; t++) {
        float a0 = nx0, a1 = nx1;
        int tn = (t + 1 < T) ? (t + 1) : t;
        nx0 = gx[((size_t)tn * NB + b) * G4 + g0];          // prefetch next step
        nx1 = gx[((size_t)tn * NB + b) * G4 + g1];
        float p0 = 0.f, q0 = 0.f, p1 = 0.f, q1 = 0.f;
        #pragma unroll
        for (int k = 0; k < NH / 2; k += 2) {
            h2v ha = hv[k], hb = hv[k + 1];
            p0 = FDOT2(w0[k],     ha, p0);
            q0 = FDOT2(w0[k + 1], hb, q0);
            p1 = FDOT2(w1[k],     ha, p1);
            q1 = FDOT2(w1[k + 1], hb, q1);
        }
        gs[g0] = a0 + p0 + q0;
        gs[g1] = a1 + p1 + q1;
        __syncthreads();
        if (t0 < NH) {
            int j = t0;
            float gi = gs[j], gf = gs[NH + j], gg = gs[2 * NH + j], go = gs[3 * NH + j];
            float si = 1.f / (1.f + __expf(-gi));
            float sf = 1.f / (1.f + __expf(-gf));
            float so = 1.f / (1.f + __expf(-go));
            c = sf * c + si * tanhf(gg);
            h = so * tanhf(c);
            h2h[j] = (_Float16)h;
        }
        __syncthreads();
    }
    if (t0 < NH) hfinal[(size_t)b * NH + t0] = h;
}

// ============================ head ============================
// pass 1: 72 blocks (9 col-groups x 8 row-groups) x 64 lanes.
// colacc[col] += sum_{rows in group} dvec[i] * m1w[i*576+col]  (coalesced rows)
__global__ __launch_bounds__(64) void k_head1(const float* dvec, const float* m1w, float* colacc) {
    int rg = blockIdx.x & 7;           // 8 row groups x 144 rows
    int cg = blockIdx.x >> 3;          // 9 col groups x 64 cols
    int col = cg * 64 + threadIdx.x;
    int r0 = rg * 144;
    float acc = 0.f;
    #pragma unroll 4
    for (int i = r0; i < r0 + 144; i++)
        acc += dvec[i] * m1w[(size_t)i * 576 + col];
    atomicAdd(&colacc[col], acc);
}

// pass 2: out = sum_col (colacc+m1b)*m2w + m2b; dual-dtype store.
__global__ __launch_bounds__(256) void k_head2(const float* colacc, const float* m1b,
                                               const float* m2w, const float* m2b,
                                               unsigned int* out) {
    __shared__ float wr[4];
    int j = threadIdx.x;
    float sum = 0.f;
    for (int col = j; col < 576; col += 256)
        sum += (colacc[col] + m1b[col]) * m2w[col];
    #pragma unroll
    for (int off = 32; off > 0; off >>= 1) sum += __shfl_down(sum, off, 64);
    if ((j & 63) == 0) wr[j >> 6] = sum;
    __syncthreads();
    if (j == 0) {
        float s = wr[0] + wr[1] + wr[2] + wr[3] + m2b[0];
        bf16 hb = __float2bfloat16(s);
        unsigned short u;
        memcpy(&u, &hb, 2);
        out[0] = ((unsigned int)u << 16) | u;
    }
}

// ============================ launcher ============================

extern "C" void kernel_launch(void* const* d_in, const int* in_sizes, int n_in,
                              void* d_out, int out_size, void* d_ws, size_t ws_size,
                              hipStream_t stream) {
    const float* data0 = (const float*)d_in[0];
    const float* data1 = (const float*)d_in[1];
    const int*   ei    = (const int*)d_in[2];
    const float* W1    = (const float*)d_in[3];
    const float* b1    = (const float*)d_in[4];
    const float* W2    = (const float*)d_in[5];
    const float* b2    = (const float*)d_in[6];
    const float* Wih1  = (const float*)d_in[7];
    const float* Whh1  = (const float*)d_in[8];
    const float* bih1  = (const float*)d_in[9];
    const float* bhh1  = (const float*)d_in[10];
    const float* Wih2  = (const float*)d_in[11];
    const float* Whh2  = (const float*)d_in[12];
    const float* bih2  = (const float*)d_in[13];
    const float* bhh2  = (const float*)d_in[14];
    const float* m1w   = (const float*)d_in[15];
    const float* m1b   = (const float*)d_in[16];
    const float* m2w   = (const float*)d_in[17];
    const float* m2b   = (const float*)d_in[18];

    const int n = in_sizes[1] / NH;       // 100000
    const int E = in_sizes[2] / 2;        // 800000 (elements; int width sniffed on device)

    char* ws = (char*)d_ws;
    float* gx1   = (float*)(ws + OFF_GX1);
    float* gx2   = (float*)(ws + OFF_GX2);
    int*   deg   = (int*)  (ws + OFF_DEG);
    float* dinv  = (float*)(ws + OFF_DINV);
    int*   slot1 = (int*)  (ws + OFF_SL1);
    int*   slot2 = (int*)  (ws + OFF_SL2);
    int*   cnt   = (int*)  (ws + OFF_CNT);
    int2*  l1    = (int2*) (ws + OFF_L1);
    int*   s1l   = (int*)  (ws + OFF_S1);
    int2*  l2    = (int2*) (ws + OFF_L2);
    int*   s2l   = (int*)  (ws + OFF_S2);
    float* xw1   = (float*)(ws + OFF_XW1);
    float* h1    = (float*)(ws + OFF_H1);
    float* xw2   = (float*)(ws + OFF_XW2);
    float* dvec  = (float*)(ws + OFF_DVEC);
    float* h1f   = (float*)(ws + OFF_H1F);
    float* cacc  = (float*)(ws + OFF_CACC);

    // diagnostic canary (overwritten by k_head2 with the real answer)
    float v = 1.0f + (ws_size < WS_NEEDED ? 1.0f : 0.0f) + (n_in != 19 ? 2.0f : 0.0f);
    unsigned int fb; memcpy(&fb, &v, 4);
    unsigned int hi = fb >> 16;
    unsigned int canary_bits = (hi << 16) | hi;
    k_canary <<<1, 64, 0, stream>>>((unsigned int*)d_out, canary_bits);

    int nb = (n + 255) / 256;
    int eb = (E + 255) / 256;

    // subgraph build
    k_init   <<<nb, 256, 0, stream>>>(ei, deg, slot1, slot2, cnt, cacc, n);
    k_deg_l1 <<<eb, 256, 0, stream>>>(ei, E, deg, l1, cnt);
    k_dinv   <<<nb, 256, 0, stream>>>(deg, dinv, n);
    k_s1     <<<1, 256, 0, stream>>>(l1, cnt, slot1, s1l);
    k_s2self <<<8, 256, 0, stream>>>(s1l, cnt, slot2, s2l);
    k_l2     <<<eb, 256, 0, stream>>>(ei, E, slot1, l2, cnt, slot2, s2l);
    // GCN compute on active subgraph
    k_xw1    <<<S2CAP, NH, 0, stream>>>(data1, W1, s2l, cnt, xw1);
    k_h1init <<<S1CAP, NH, 0, stream>>>(xw1, s1l, cnt, slot2, dinv, h1);
    k_h1scat <<<LCAP2, NH, 0, stream>>>(xw1, l2, cnt, slot1, slot2, dinv, h1);
    k_xw2    <<<S1CAP, NH, 0, stream>>>(h1, W2, b1, cnt, xw2);
    k_gout   <<<NTGT, NH, 0, stream>>>(xw2, l1, cnt, slot1, dinv, b2, dvec);
    // LSTM path
    k_gx1    <<<TSEQ * BBATCH / 32, 256, 0, stream>>>(data0, Wih1, bih1, bhh1, gx1);
    k_lstm<TSEQ, BBATCH><<<BBATCH, 256, 0, stream>>>(gx1, Whh1, h1f);
    k_gx2    <<<BBATCH, 256, 0, stream>>>(h1f, Wih2, bih2, bhh2, gx2);
    k_lstm<BBATCH, 1>  <<<1, 256, 0, stream>>>(gx2, Whh2, dvec + 1024);
    // head
    k_head1  <<<72, 64, 0, stream>>>(dvec, m1w, cacc);
    k_head2  <<<1, 256, 0, stream>>>(cacc, m1b, m2w, m2b, (unsigned int*)d_out);
    (void)out_size;
}

// Round 9
// 443.705 us; speedup vs baseline: 2.3893x; 1.4714x over previous
//
#include <hip/hip_runtime.h>
#include <hip/hip_bf16.h>
#include <cstring>

using bf16 = __hip_bfloat16;
typedef _Float16 h2v __attribute__((ext_vector_type(2)));

#if __has_builtin(__builtin_amdgcn_fdot2)
__device__ __forceinline__ float FDOT2(h2v a, h2v b, float c) {
    return __builtin_amdgcn_fdot2(a, b, c, false);
}
#else
__device__ __forceinline__ float FDOT2(h2v a, h2v b, float c) {
    return c + (float)a.x * (float)b.x + (float)a.y * (float)b.y;
}
#endif

// ---- problem constants ----
constexpr int NH    = 128;    // hidden
constexpr int G4    = 512;    // 4*H gates
constexpr int TSEQ  = 200;
constexpr int BBATCH= 32;
constexpr int NTGT  = 8;

// ---- subgraph caps (Poisson means: |L1|~64, |S1|~72, |L2|~580, |S2|~650) ----
constexpr int LCAP1 = 1024;
constexpr int S1CAP = LCAP1 + NTGT;
constexpr int LCAP2 = 8192;
constexpr int S2CAP = LCAP2 + S1CAP;

// ---- workspace layout (bytes) ----
constexpr size_t algn(size_t x) { return (x + 255) & ~size_t(255); }
constexpr size_t OFF_GX1  = 0;                                            // 6400*512 f32
constexpr size_t OFF_GX2  = algn(OFF_GX1  + 6400ull * G4 * 4);            // 32*512 f32
constexpr size_t OFF_DEG  = algn(OFF_GX2  + 32ull * G4 * 4);              // N i32
constexpr size_t OFF_DINV = algn(OFF_DEG  + 100000ull * 4);               // N f32
constexpr size_t OFF_SL1  = algn(OFF_DINV + 100000ull * 4);               // N i32
constexpr size_t OFF_SL2  = algn(OFF_SL1  + 100000ull * 4);               // N i32
constexpr size_t OFF_CNT  = algn(OFF_SL2  + 100000ull * 4);               // 16 i32
constexpr size_t OFF_L1   = algn(OFF_CNT  + 64);                          // LCAP1 int2
constexpr size_t OFF_S1   = algn(OFF_L1   + (size_t)LCAP1 * 8);           // S1CAP i32
constexpr size_t OFF_L2   = algn(OFF_S1   + (size_t)S1CAP * 4);           // LCAP2 int2
constexpr size_t OFF_S2   = algn(OFF_L2   + (size_t)LCAP2 * 8);           // S2CAP i32
constexpr size_t OFF_XW1  = algn(OFF_S2   + (size_t)S2CAP * 4);           // S2CAP*128 f32
constexpr size_t OFF_H1   = algn(OFF_XW1  + (size_t)S2CAP * NH * 4);      // S1CAP*128 f32
constexpr size_t OFF_XW2  = algn(OFF_H1   + (size_t)S1CAP * NH * 4);      // S1CAP*128 f32
constexpr size_t OFF_DVEC = algn(OFF_XW2  + (size_t)S1CAP * NH * 4);      // 1152 f32
constexpr size_t OFF_H1F  = algn(OFF_DVEC + 1152ull * 4);                 // 32*128 f32
constexpr size_t OFF_CACC = algn(OFF_H1F  + 32ull * NH * 4);              // 576 f32
constexpr size_t WS_NEEDED = OFF_CACC + 576ull * 4;

// edge_index may be staged as int64 (reference dtype) or int32. If int64,
// odd int32 words are the (all-zero) high halves. cnt[15] = sniffed flag.
__device__ __forceinline__ int edge_at(const int* ei, int E, int is64, int row, int e) {
    return is64 ? ei[(((size_t)row * E) + e) * 2] : ei[((size_t)row * E) + e];
}

// ============================ diagnostic canary ============================
__global__ void k_canary(unsigned int* out, unsigned int bits) {
    if (threadIdx.x == 0) out[0] = bits;
}

// ============================ GCN subgraph build ============================

__global__ void k_init(const int* ei, int* deg, int* slot1, int* slot2, int* cnt,
                       float* colacc, int n) {
    int i = blockIdx.x * 256 + threadIdx.x;
    if (i < 14) cnt[i] = 0;
    if (i == 15) cnt[15] = (ei[1] == 0 && ei[3] == 0 && ei[5] == 0 && ei[7] == 0) ? 1 : 0;
    if (i < 576) colacc[i] = 0.f;
    for (; i < n; i += gridDim.x * 256) { deg[i] = 0; slot1[i] = -1; slot2[i] = -1; }
}

__global__ void k_deg_l1(const int* ei, int E, int* deg, int2* l1, int* cnt) {
    int is64 = cnt[15];
    for (int e = blockIdx.x * 256 + threadIdx.x; e < E; e += gridDim.x * 256) {
        int d = edge_at(ei, E, is64, 1, e);
        if ((unsigned)d < 100000u) atomicAdd(&deg[d], 1);
        if (d <= 7000 && d >= 0 && d % 1000 == 0) {          // d in TARGET
            int s = edge_at(ei, E, is64, 0, e);
            int idx = atomicAdd(&cnt[0], 1);
            if (idx < LCAP1) l1[idx] = make_int2(s, d);
        }
    }
}

__global__ void k_dinv(const int* deg, float* dinv, int n) {
    for (int i = blockIdx.x * 256 + threadIdx.x; i < n; i += gridDim.x * 256)
        dinv[i] = rsqrtf((float)deg[i] + 1.0f);
}

__global__ void k_s1(const int2* l1, int* cnt, int* slot1, int* s1list) {
    int m = min(cnt[0], LCAP1);
    for (int i = threadIdx.x; i < NTGT + m; i += blockDim.x) {
        int v = (i < NTGT) ? i * 1000 : l1[i - NTGT].x;
        if ((unsigned)v >= 100000u) continue;
        int old = atomicCAS(&slot1[v], -1, -2);
        if (old == -1) {
            int idx = atomicAdd(&cnt[1], 1);
            if (idx < S1CAP) { s1list[idx] = v; atomicExch(&slot1[v], idx); }
        }
    }
}

__global__ void k_s2self(const int* s1list, int* cnt, int* slot2, int* s2list) {
    int nS1 = min(cnt[1], S1CAP);
    for (int i = blockIdx.x * 256 + threadIdx.x; i < nS1; i += gridDim.x * 256) {
        int v = s1list[i];
        int old = atomicCAS(&slot2[v], -1, -2);
        if (old == -1) {
            int idx = atomicAdd(&cnt[2], 1);
            if (idx < S2CAP) { s2list[idx] = v; atomicExch(&slot2[v], idx); }
        }
    }
}

__global__ void k_l2(const int* ei, int E, const int* slot1,
                     int2* l2, int* cnt, int* slot2, int* s2list) {
    int is64 = cnt[15];
    for (int e = blockIdx.x * 256 + threadIdx.x; e < E; e += gridDim.x * 256) {
        int d = edge_at(ei, E, is64, 1, e);
        if ((unsigned)d >= 100000u) continue;
        if (slot1[d] >= 0) {
            int s = edge_at(ei, E, is64, 0, e);
            if ((unsigned)s >= 100000u) continue;
            int idx = atomicAdd(&cnt[3], 1);
            if (idx < LCAP2) l2[idx] = make_int2(s, d);
            int old = atomicCAS(&slot2[s], -1, -2);
            if (old == -1) {
                int j = atomicAdd(&cnt[2], 1);
                if (j < S2CAP) { s2list[j] = s; atomicExch(&slot2[s], j); }
            }
        }
    }
}

// ============================ GCN compute (fp32 inputs) ============================

__global__ void k_xw1(const float* x, const float* W, const int* s2list, const int* cnt, float* xw1) {
    int i = blockIdx.x;
    if (i >= min(cnt[2], S2CAP)) return;
    int node = s2list[i];
    __shared__ float xs[NH];
    int c = threadIdx.x;
    xs[c] = x[(size_t)node * NH + c];
    __syncthreads();
    float acc = 0.f;
    #pragma unroll 8
    for (int k = 0; k < NH; k++) acc += xs[k] * W[(size_t)k * NH + c];
    xw1[(size_t)i * NH + c] = acc;
}

__global__ void k_h1init(const float* xw1, const int* s1list, const int* cnt,
                         const int* slot2, const float* dinv, float* h1) {
    int i = blockIdx.x;
    if (i >= min(cnt[1], S1CAP)) return;
    int node = s1list[i];
    int s2 = slot2[node];
    if (s2 < 0 || s2 >= S2CAP) s2 = 0;
    float v = dinv[node];
    h1[i * NH + threadIdx.x] = xw1[(size_t)s2 * NH + threadIdx.x] * v * v;
}

__global__ void k_h1scat(const float* xw1, const int2* l2, const int* cnt,
                         const int* slot1, const int* slot2, const float* dinv, float* h1) {
    int e = blockIdx.x;
    if (e >= min(cnt[3], LCAP2)) return;
    int2 sd = l2[e];
    int t1 = slot1[sd.y], s2 = slot2[sd.x];
    if (t1 < 0 || t1 >= S1CAP || s2 < 0 || s2 >= S2CAP) return;
    float w = dinv[sd.x] * dinv[sd.y];
    atomicAdd(&h1[t1 * NH + threadIdx.x],
              xw1[(size_t)s2 * NH + threadIdx.x] * w);
}

// fused: relu(h1 + b1) then @ W2
__global__ void k_xw2(const float* h1, const float* W, const float* b1, const int* cnt, float* xw2) {
    int i = blockIdx.x;
    if (i >= min(cnt[1], S1CAP)) return;
    __shared__ float xs[NH];
    int c = threadIdx.x;
    xs[c] = fmaxf(h1[i * NH + c] + b1[c], 0.f);
    __syncthreads();
    float acc = 0.f;
    #pragma unroll 8
    for (int k = 0; k < NH; k++) acc += xs[k] * W[(size_t)k * NH + c];
    xw2[(size_t)i * NH + c] = acc;
}

__global__ void k_gout(const float* xw2, const int2* l1, const int* cnt,
                       const int* slot1, const float* dinv, const float* b2, float* dvec) {
    int t = blockIdx.x;             // 0..7
    int tgt = t * 1000;
    int c = threadIdx.x;
    float vt = dinv[tgt];
    int st = slot1[tgt]; if (st < 0 || st >= S1CAP) st = 0;
    float acc = xw2[(size_t)st * NH + c] * vt * vt;
    int m = min(cnt[0], LCAP1);
    for (int e = 0; e < m; e++) {
        int2 sd = l1[e];
        if (sd.y == tgt) {
            int ss = slot1[sd.x];
            if (ss >= 0 && ss < S1CAP)
                acc += xw2[(size_t)ss * NH + c] * dinv[sd.x] * vt;
        }
    }
    acc += b2[c];
    dvec[t * NH + c] = fmaxf(acc, 0.f);
}

// ============================ LSTM (fp32 inputs) ============================

// gx1 = data0_rows @ Wih1^T + bias, as LDS-tiled GEMM.
// M=6400 (r=t*32+b), N=512 gates, K=64. Grid 100x8 blocks of 64x64 tile.
// R8 fix: the old per-thread w0[64]/w1[64] arrays spilled (VGPR_Count=64,
// FETCH 54MB / WRITE 47MB scratch traffic, 240 us). Tile keeps ~40 VGPRs.
__global__ __launch_bounds__(256) void k_gx1(const float* data0, const float* Wih,
                                             const float* bih, const float* bhh, float* gx) {
    constexpr int LDP = 68;                       // pad 64->68 breaks bank conflicts
    __shared__ float As[64 * LDP];                // rows x k
    __shared__ float Bs[64 * LDP];                // gates x k
    int tid = threadIdx.x;
    int rb = blockIdx.x >> 3;                     // 0..99  row block
    int gb = blockIdx.x & 7;                      // 0..7   gate block
    int r0 = rb * 64, g0 = gb * 64;
    for (int i = tid; i < 64 * 64; i += 256) {
        int rr = i >> 6, k = i & 63;
        int r = r0 + rr, b = r & 31, t = r >> 5;
        As[rr * LDP + k] = data0[((size_t)b * TSEQ + t) * 64 + k];
        Bs[rr * LDP + k] = Wih[(size_t)(g0 + rr) * 64 + k];
    }
    __syncthreads();
    int tr = (tid & 15) * 4;                      // 4 rows
    int tg = (tid >> 4) * 4;                      // 4 gates
    float acc[4][4] = {};
    #pragma unroll
    for (int k4 = 0; k4 < 16; k4++) {
        float4 a0 = *(const float4*)&As[(tr + 0) * LDP + k4 * 4];
        float4 a1 = *(const float4*)&As[(tr + 1) * LDP + k4 * 4];
        float4 a2 = *(const float4*)&As[(tr + 2) * LDP + k4 * 4];
        float4 a3 = *(const float4*)&As[(tr + 3) * LDP + k4 * 4];
        float4 b0 = *(const float4*)&Bs[(tg + 0) * LDP + k4 * 4];
        float4 b1 = *(const float4*)&Bs[(tg + 1) * LDP + k4 * 4];
        float4 b2 = *(const float4*)&Bs[(tg + 2) * LDP + k4 * 4];
        float4 b3 = *(const float4*)&Bs[(tg + 3) * LDP + k4 * 4];
        const float4 av[4] = {a0, a1, a2, a3};
        const float4 bv[4] = {b0, b1, b2, b3};
        #pragma unroll
        for (int i = 0; i < 4; i++)
            #pragma unroll
            for (int j = 0; j < 4; j++)
                acc[i][j] += av[i].x * bv[j].x + av[i].y * bv[j].y
                           + av[i].z * bv[j].z + av[i].w * bv[j].w;
    }
    float bias[4];
    #pragma unroll
    for (int j = 0; j < 4; j++) bias[j] = bih[g0 + tg + j] + bhh[g0 + tg + j];
    #pragma unroll
    for (int i = 0; i < 4; i++) {
        size_t row = (size_t)(r0 + tr + i) * G4 + g0 + tg;
        #pragma unroll
        for (int j = 0; j < 4; j++) gx[row + j] = acc[i][j] + bias[j];
    }
}

// gx2[t][g] = h1f[t][:] . Wih2[g][:] + biases; 256 thr, 2 gates.
__global__ void k_gx2(const float* h1f, const float* Wih,
                      const float* bih, const float* bhh, float* gx) {
    int t = blockIdx.x;
    __shared__ float xs[NH];
    int tid = threadIdx.x;
    int g0 = tid, g1 = tid + 256;
    if (tid < NH) xs[tid] = h1f[t * NH + tid];
    __syncthreads();
    float a0 = bih[g0] + bhh[g0];
    float a1 = bih[g1] + bhh[g1];
    #pragma unroll 4
    for (int k = 0; k < NH; k++) {
        a0 += Wih[(size_t)g0 * NH + k] * xs[k];
        a1 += Wih[(size_t)g1 * NH + k] * xs[k];
    }
    gx[(size_t)t * G4 + g0] = a0;
    gx[(size_t)t * G4 + g1] = a1;
}

// recurrence: 1 block/batch, 256 thr, 2 gates/thread. Weights as fp16 half2
// in VGPRs (64 dwords/gate); h broadcast as packed fp16 in LDS; fp32 math.
template<int T, int NB>
__global__ __launch_bounds__(256, 1) void k_lstm(const float* gx, const float* Whh, float* hfinal) {
    int b = blockIdx.x;
    int t0 = threadIdx.x;
    int g0 = t0, g1 = t0 + 256;
    __shared__ __align__(16) _Float16 h2h[NH];
    __shared__ float gs[G4];
    h2v w0[NH / 2], w1[NH / 2];
    #pragma unroll
    for (int k = 0; k < NH; k += 4) {
        float4 a = *(const float4*)&Whh[(size_t)g0 * NH + k];
        w0[k / 2]     = h2v{(_Float16)a.x, (_Float16)a.y};
        w0[k / 2 + 1] = h2v{(_Float16)a.z, (_Float16)a.w};
        float4 c4 = *(const float4*)&Whh[(size_t)g1 * NH + k];
        w1[k / 2]     = h2v{(_Float16)c4.x, (_Float16)c4.y};
        w1[k / 2 + 1] = h2v{(_Float16)c4.z, (_Float16)c4.w};
    }
    if (t0 < NH) h2h[t0] = (_Float16)0.f;
    float c = 0.f, h = 0.f;
    float nx0 = gx[((size_t)0 * NB + b) * G4 + g0];
    float nx1 = gx[((size_t)0 * NB + b) * G4 + g1];
    __syncthreads();
    const h2v* hv = (const h2v*)h2h;
    for (int t = 0; t < T; t++) {
        float a0 = nx0, a1 = nx1;
        int tn = (t + 1 < T) ? (t + 1) : t;
        nx0 = gx[((size_t)tn * NB + b) * G4 + g0];          // prefetch next step
        nx1 = gx[((size_t)tn * NB + b) * G4 + g1];
        float p0 = 0.f, q0 = 0.f, p1 = 0.f, q1 = 0.f;
        #pragma unroll
        for (int k = 0; k < NH / 2; k += 2) {
            h2v ha = hv[k], hb = hv[k + 1];
            p0 = FDOT2(w0[k],     ha, p0);
            q0 = FDOT2(w0[k + 1], hb, q0);
            p1 = FDOT2(w1[k],     ha, p1);
            q1 = FDOT2(w1[k + 1], hb, q1);
        }
        gs[g0] = a0 + p0 + q0;
        gs[g1] = a1 + p1 + q1;
        __syncthreads();
        if (t0 < NH) {
            int j = t0;
            float gi = gs[j], gf = gs[NH + j], gg = gs[2 * NH + j], go = gs[3 * NH + j];
            float si = 1.f / (1.f + __expf(-gi));
            float sf = 1.f / (1.f + __expf(-gf));
            float so = 1.f / (1.f + __expf(-go));
            c = sf * c + si * tanhf(gg);
            h = so * tanhf(c);
            h2h[j] = (_Float16)h;
        }
        __syncthreads();
    }
    if (t0 < NH) hfinal[(size_t)b * NH + t0] = h;
}

// ============================ head ============================
// pass 1: 72 blocks (9 col-groups x 8 row-groups) x 64 lanes.
__global__ __launch_bounds__(64) void k_head1(const float* dvec, const float* m1w, float* colacc) {
    int rg = blockIdx.x & 7;           // 8 row groups x 144 rows
    int cg = blockIdx.x >> 3;          // 9 col groups x 64 cols
    int col = cg * 64 + threadIdx.x;
    int r0 = rg * 144;
    float acc = 0.f;
    #pragma unroll 4
    for (int i = r0; i < r0 + 144; i++)
        acc += dvec[i] * m1w[(size_t)i * 576 + col];
    atomicAdd(&colacc[col], acc);
}

// pass 2: out = sum_col (colacc+m1b)*m2w + m2b; dual-dtype store.
__global__ __launch_bounds__(256) void k_head2(const float* colacc, const float* m1b,
                                               const float* m2w, const float* m2b,
                                               unsigned int* out) {
    __shared__ float wr[4];
    int j = threadIdx.x;
    float sum = 0.f;
    for (int col = j; col < 576; col += 256)
        sum += (colacc[col] + m1b[col]) * m2w[col];
    #pragma unroll
    for (int off = 32; off > 0; off >>= 1) sum += __shfl_down(sum, off, 64);
    if ((j & 63) == 0) wr[j >> 6] = sum;
    __syncthreads();
    if (j == 0) {
        float s = wr[0] + wr[1] + wr[2] + wr[3] + m2b[0];
        bf16 hb = __float2bfloat16(s);
        unsigned short u;
        memcpy(&u, &hb, 2);
        out[0] = ((unsigned int)u << 16) | u;
    }
}

// ============================ launcher ============================

extern "C" void kernel_launch(void* const* d_in, const int* in_sizes, int n_in,
                              void* d_out, int out_size, void* d_ws, size_t ws_size,
                              hipStream_t stream) {
    const float* data0 = (const float*)d_in[0];
    const float* data1 = (const float*)d_in[1];
    const int*   ei    = (const int*)d_in[2];
    const float* W1    = (const float*)d_in[3];
    const float* b1    = (const float*)d_in[4];
    const float* W2    = (const float*)d_in[5];
    const float* b2    = (const float*)d_in[6];
    const float* Wih1  = (const float*)d_in[7];
    const float* Whh1  = (const float*)d_in[8];
    const float* bih1  = (const float*)d_in[9];
    const float* bhh1  = (const float*)d_in[10];
    const float* Wih2  = (const float*)d_in[11];
    const float* Whh2  = (const float*)d_in[12];
    const float* bih2  = (const float*)d_in[13];
    const float* bhh2  = (const float*)d_in[14];
    const float* m1w   = (const float*)d_in[15];
    const float* m1b   = (const float*)d_in[16];
    const float* m2w   = (const float*)d_in[17];
    const float* m2b   = (const float*)d_in[18];

    const int n = in_sizes[1] / NH;       // 100000
    const int E = in_sizes[2] / 2;        // 800000 (elements; int width sniffed on device)

    char* ws = (char*)d_ws;
    float* gx1   = (float*)(ws + OFF_GX1);
    float* gx2   = (float*)(ws + OFF_GX2);
    int*   deg   = (int*)  (ws + OFF_DEG);
    float* dinv  = (float*)(ws + OFF_DINV);
    int*   slot1 = (int*)  (ws + OFF_SL1);
    int*   slot2 = (int*)  (ws + OFF_SL2);
    int*   cnt   = (int*)  (ws + OFF_CNT);
    int2*  l1    = (int2*) (ws + OFF_L1);
    int*   s1l   = (int*)  (ws + OFF_S1);
    int2*  l2    = (int2*) (ws + OFF_L2);
    int*   s2l   = (int*)  (ws + OFF_S2);
    float* xw1   = (float*)(ws + OFF_XW1);
    float* h1    = (float*)(ws + OFF_H1);
    float* xw2   = (float*)(ws + OFF_XW2);
    float* dvec  = (float*)(ws + OFF_DVEC);
    float* h1f   = (float*)(ws + OFF_H1F);
    float* cacc  = (float*)(ws + OFF_CACC);

    // diagnostic canary (overwritten by k_head2 with the real answer)
    float v = 1.0f + (ws_size < WS_NEEDED ? 1.0f : 0.0f) + (n_in != 19 ? 2.0f : 0.0f);
    unsigned int fb; memcpy(&fb, &v, 4);
    unsigned int hi = fb >> 16;
    unsigned int canary_bits = (hi << 16) | hi;
    k_canary <<<1, 64, 0, stream>>>((unsigned int*)d_out, canary_bits);

    int nb = (n + 255) / 256;
    int eb = (E + 255) / 256;

    // subgraph build
    k_init   <<<nb, 256, 0, stream>>>(ei, deg, slot1, slot2, cnt, cacc, n);
    k_deg_l1 <<<eb, 256, 0, stream>>>(ei, E, deg, l1, cnt);
    k_dinv   <<<nb, 256, 0, stream>>>(deg, dinv, n);
    k_s1     <<<1, 256, 0, stream>>>(l1, cnt, slot1, s1l);
    k_s2self <<<8, 256, 0, stream>>>(s1l, cnt, slot2, s2l);
    k_l2     <<<eb, 256, 0, stream>>>(ei, E, slot1, l2, cnt, slot2, s2l);
    // GCN compute on active subgraph
    k_xw1    <<<S2CAP, NH, 0, stream>>>(data1, W1, s2l, cnt, xw1);
    k_h1init <<<S1CAP, NH, 0, stream>>>(xw1, s1l, cnt, slot2, dinv, h1);
    k_h1scat <<<LCAP2, NH, 0, stream>>>(xw1, l2, cnt, slot1, slot2, dinv, h1);
    k_xw2    <<<S1CAP, NH, 0, stream>>>(h1, W2, b1, cnt, xw2);
    k_gout   <<<NTGT, NH, 0, stream>>>(xw2, l1, cnt, slot1, dinv, b2, dvec);
    // LSTM path
    k_gx1    <<<800, 256, 0, stream>>>(data0, Wih1, bih1, bhh1, gx1);
    k_lstm<TSEQ, BBATCH><<<BBATCH, 256, 0, stream>>>(gx1, Whh1, h1f);
    k_gx2    <<<BBATCH, 256, 0, stream>>>(h1f, Wih2, bih2, bhh2, gx2);
    k_lstm<BBATCH, 1>  <<<1, 256, 0, stream>>>(gx2, Whh2, dvec + 1024);
    // head
    k_head1  <<<72, 64, 0, stream>>>(dvec, m1w, cacc);
    k_head2  <<<1, 256, 0, stream>>>(cacc, m1b, m2w, m2b, (unsigned int*)d_out);
    (void)out_size;
}

// Round 10
// 412.177 us; speedup vs baseline: 2.5720x; 1.0765x over previous
//
#include <hip/hip_runtime.h>
#include <hip/hip_bf16.h>
#include <cstring>

using bf16 = __hip_bfloat16;
typedef _Float16 h2v __attribute__((ext_vector_type(2)));
typedef _Float16 h8v __attribute__((ext_vector_type(8)));

#if __has_builtin(__builtin_amdgcn_fdot2)
__device__ __forceinline__ float FDOT2(h2v a, h2v b, float c) {
    return __builtin_amdgcn_fdot2(a, b, c, false);
}
#else
__device__ __forceinline__ float FDOT2(h2v a, h2v b, float c) {
    return c + (float)a.x * (float)b.x + (float)a.y * (float)b.y;
}
#endif

// fast sigmoid/tanh: v_exp_f32 + v_rcp_f32, saturate correctly at +-inf, no NaN.
__device__ __forceinline__ float sigm_f(float x) {
    return __builtin_amdgcn_rcpf(1.f + __expf(-x));
}
__device__ __forceinline__ float tanh_f(float x) {
    return 1.f - 2.f * __builtin_amdgcn_rcpf(1.f + __expf(2.f * x));
}

// ---- problem constants ----
constexpr int NH    = 128;    // hidden
constexpr int G4    = 512;    // 4*H gates
constexpr int TSEQ  = 200;
constexpr int BBATCH= 32;
constexpr int NTGT  = 8;

// ---- subgraph caps (Poisson means: |L1|~64, |S1|~72, |L2|~580, |S2|~650) ----
constexpr int LCAP1 = 1024;
constexpr int S1CAP = LCAP1 + NTGT;
constexpr int LCAP2 = 8192;
constexpr int S2CAP = LCAP2 + S1CAP;

// ---- workspace layout (bytes) ----
constexpr size_t algn(size_t x) { return (x + 255) & ~size_t(255); }
constexpr size_t OFF_GX1  = 0;                                            // 6400*512 f32
constexpr size_t OFF_GX2  = algn(OFF_GX1  + 6400ull * G4 * 4);            // 32*512 f32
constexpr size_t OFF_DEG  = algn(OFF_GX2  + 32ull * G4 * 4);              // N i32
constexpr size_t OFF_DINV = algn(OFF_DEG  + 100000ull * 4);               // N f32
constexpr size_t OFF_SL1  = algn(OFF_DINV + 100000ull * 4);               // N i32
constexpr size_t OFF_SL2  = algn(OFF_SL1  + 100000ull * 4);               // N i32
constexpr size_t OFF_CNT  = algn(OFF_SL2  + 100000ull * 4);               // 16 i32
constexpr size_t OFF_L1   = algn(OFF_CNT  + 64);                          // LCAP1 int2
constexpr size_t OFF_S1   = algn(OFF_L1   + (size_t)LCAP1 * 8);           // S1CAP i32
constexpr size_t OFF_L2   = algn(OFF_S1   + (size_t)S1CAP * 4);           // LCAP2 int2
constexpr size_t OFF_S2   = algn(OFF_L2   + (size_t)LCAP2 * 8);           // S2CAP i32
constexpr size_t OFF_XW1  = algn(OFF_S2   + (size_t)S2CAP * 4);           // S2CAP*128 f32
constexpr size_t OFF_H1   = algn(OFF_XW1  + (size_t)S2CAP * NH * 4);      // S1CAP*128 f32
constexpr size_t OFF_XW2  = algn(OFF_H1   + (size_t)S1CAP * NH * 4);      // S1CAP*128 f32
constexpr size_t OFF_DVEC = algn(OFF_XW2  + (size_t)S1CAP * NH * 4);      // 1152 f32
constexpr size_t OFF_H1F  = algn(OFF_DVEC + 1152ull * 4);                 // 32*128 f32
constexpr size_t OFF_CACC = algn(OFF_H1F  + 32ull * NH * 4);              // 576 f32
constexpr size_t WS_NEEDED = OFF_CACC + 576ull * 4;

// edge_index may be staged as int64 (reference dtype) or int32. If int64,
// odd int32 words are the (all-zero) high halves. cnt[15] = sniffed flag.
__device__ __forceinline__ int edge_at(const int* ei, int E, int is64, int row, int e) {
    return is64 ? ei[(((size_t)row * E) + e) * 2] : ei[((size_t)row * E) + e];
}

// ============================ diagnostic canary ============================
__global__ void k_canary(unsigned int* out, unsigned int bits) {
    if (threadIdx.x == 0) out[0] = bits;
}

// ============================ GCN subgraph build ============================

__global__ void k_init(const int* ei, int* deg, int* slot1, int* slot2, int* cnt,
                       float* colacc, int n) {
    int i = blockIdx.x * 256 + threadIdx.x;
    if (i < 14) cnt[i] = 0;
    if (i == 15) cnt[15] = (ei[1] == 0 && ei[3] == 0 && ei[5] == 0 && ei[7] == 0) ? 1 : 0;
    if (i < 576) colacc[i] = 0.f;
    for (; i < n; i += gridDim.x * 256) { deg[i] = 0; slot1[i] = -1; slot2[i] = -1; }
}

__global__ void k_deg_l1(const int* ei, int E, int* deg, int2* l1, int* cnt) {
    int is64 = cnt[15];
    for (int e = blockIdx.x * 256 + threadIdx.x; e < E; e += gridDim.x * 256) {
        int d = edge_at(ei, E, is64, 1, e);
        if ((unsigned)d < 100000u) atomicAdd(&deg[d], 1);
        if (d <= 7000 && d >= 0 && d % 1000 == 0) {          // d in TARGET
            int s = edge_at(ei, E, is64, 0, e);
            int idx = atomicAdd(&cnt[0], 1);
            if (idx < LCAP1) l1[idx] = make_int2(s, d);
        }
    }
}

__global__ void k_dinv(const int* deg, float* dinv, int n) {
    for (int i = blockIdx.x * 256 + threadIdx.x; i < n; i += gridDim.x * 256)
        dinv[i] = rsqrtf((float)deg[i] + 1.0f);
}

__global__ void k_s1(const int2* l1, int* cnt, int* slot1, int* s1list) {
    int m = min(cnt[0], LCAP1);
    for (int i = threadIdx.x; i < NTGT + m; i += blockDim.x) {
        int v = (i < NTGT) ? i * 1000 : l1[i - NTGT].x;
        if ((unsigned)v >= 100000u) continue;
        int old = atomicCAS(&slot1[v], -1, -2);
        if (old == -1) {
            int idx = atomicAdd(&cnt[1], 1);
            if (idx < S1CAP) { s1list[idx] = v; atomicExch(&slot1[v], idx); }
        }
    }
}

__global__ void k_s2self(const int* s1list, int* cnt, int* slot2, int* s2list) {
    int nS1 = min(cnt[1], S1CAP);
    for (int i = blockIdx.x * 256 + threadIdx.x; i < nS1; i += gridDim.x * 256) {
        int v = s1list[i];
        int old = atomicCAS(&slot2[v], -1, -2);
        if (old == -1) {
            int idx = atomicAdd(&cnt[2], 1);
            if (idx < S2CAP) { s2list[idx] = v; atomicExch(&slot2[v], idx); }
        }
    }
}

__global__ void k_l2(const int* ei, int E, const int* slot1,
                     int2* l2, int* cnt, int* slot2, int* s2list) {
    int is64 = cnt[15];
    for (int e = blockIdx.x * 256 + threadIdx.x; e < E; e += gridDim.x * 256) {
        int d = edge_at(ei, E, is64, 1, e);
        if ((unsigned)d >= 100000u) continue;
        if (slot1[d] >= 0) {
            int s = edge_at(ei, E, is64, 0, e);
            if ((unsigned)s >= 100000u) continue;
            int idx = atomicAdd(&cnt[3], 1);
            if (idx < LCAP2) l2[idx] = make_int2(s, d);
            int old = atomicCAS(&slot2[s], -1, -2);
            if (old == -1) {
                int j = atomicAdd(&cnt[2], 1);
                if (j < S2CAP) { s2list[j] = s; atomicExch(&slot2[s], j); }
            }
        }
    }
}

// ============================ GCN compute (fp32 inputs) ============================

__global__ void k_xw1(const float* x, const float* W, const int* s2list, const int* cnt, float* xw1) {
    int i = blockIdx.x;
    if (i >= min(cnt[2], S2CAP)) return;
    int node = s2list[i];
    __shared__ float xs[NH];
    int c = threadIdx.x;
    xs[c] = x[(size_t)node * NH + c];
    __syncthreads();
    float acc = 0.f;
    #pragma unroll 8
    for (int k = 0; k < NH; k++) acc += xs[k] * W[(size_t)k * NH + c];
    xw1[(size_t)i * NH + c] = acc;
}

__global__ void k_h1init(const float* xw1, const int* s1list, const int* cnt,
                         const int* slot2, const float* dinv, float* h1) {
    int i = blockIdx.x;
    if (i >= min(cnt[1], S1CAP)) return;
    int node = s1list[i];
    int s2 = slot2[node];
    if (s2 < 0 || s2 >= S2CAP) s2 = 0;
    float v = dinv[node];
    h1[i * NH + threadIdx.x] = xw1[(size_t)s2 * NH + threadIdx.x] * v * v;
}

__global__ void k_h1scat(const float* xw1, const int2* l2, const int* cnt,
                         const int* slot1, const int* slot2, const float* dinv, float* h1) {
    int e = blockIdx.x;
    if (e >= min(cnt[3], LCAP2)) return;
    int2 sd = l2[e];
    int t1 = slot1[sd.y], s2 = slot2[sd.x];
    if (t1 < 0 || t1 >= S1CAP || s2 < 0 || s2 >= S2CAP) return;
    float w = dinv[sd.x] * dinv[sd.y];
    atomicAdd(&h1[t1 * NH + threadIdx.x],
              xw1[(size_t)s2 * NH + threadIdx.x] * w);
}

// fused: relu(h1 + b1) then @ W2
__global__ void k_xw2(const float* h1, const float* W, const float* b1, const int* cnt, float* xw2) {
    int i = blockIdx.x;
    if (i >= min(cnt[1], S1CAP)) return;
    __shared__ float xs[NH];
    int c = threadIdx.x;
    xs[c] = fmaxf(h1[i * NH + c] + b1[c], 0.f);
    __syncthreads();
    float acc = 0.f;
    #pragma unroll 8
    for (int k = 0; k < NH; k++) acc += xs[k] * W[(size_t)k * NH + c];
    xw2[(size_t)i * NH + c] = acc;
}

__global__ void k_gout(const float* xw2, const int2* l1, const int* cnt,
                       const int* slot1, const float* dinv, const float* b2, float* dvec) {
    int t = blockIdx.x;             // 0..7
    int tgt = t * 1000;
    int c = threadIdx.x;
    float vt = dinv[tgt];
    int st = slot1[tgt]; if (st < 0 || st >= S1CAP) st = 0;
    float acc = xw2[(size_t)st * NH + c] * vt * vt;
    int m = min(cnt[0], LCAP1);
    for (int e = 0; e < m; e++) {
        int2 sd = l1[e];
        if (sd.y == tgt) {
            int ss = slot1[sd.x];
            if (ss >= 0 && ss < S1CAP)
                acc += xw2[(size_t)ss * NH + c] * dinv[sd.x] * vt;
        }
    }
    acc += b2[c];
    dvec[t * NH + c] = fmaxf(acc, 0.f);
}

// ============================ LSTM (fp32 inputs) ============================

// gx1 = data0_rows @ Wih1^T + bias, LDS-tiled GEMM (R8 fix for spill).
__global__ __launch_bounds__(256) void k_gx1(const float* data0, const float* Wih,
                                             const float* bih, const float* bhh, float* gx) {
    constexpr int LDP = 68;                       // pad 64->68 breaks bank conflicts
    __shared__ float As[64 * LDP];                // rows x k
    __shared__ float Bs[64 * LDP];                // gates x k
    int tid = threadIdx.x;
    int rb = blockIdx.x >> 3;                     // 0..99  row block
    int gb = blockIdx.x & 7;                      // 0..7   gate block
    int r0 = rb * 64, g0 = gb * 64;
    for (int i = tid; i < 64 * 64; i += 256) {
        int rr = i >> 6, k = i & 63;
        int r = r0 + rr, b = r & 31, t = r >> 5;
        As[rr * LDP + k] = data0[((size_t)b * TSEQ + t) * 64 + k];
        Bs[rr * LDP + k] = Wih[(size_t)(g0 + rr) * 64 + k];
    }
    __syncthreads();
    int tr = (tid & 15) * 4;                      // 4 rows
    int tg = (tid >> 4) * 4;                      // 4 gates
    float acc[4][4] = {};
    #pragma unroll
    for (int k4 = 0; k4 < 16; k4++) {
        float4 a0 = *(const float4*)&As[(tr + 0) * LDP + k4 * 4];
        float4 a1 = *(const float4*)&As[(tr + 1) * LDP + k4 * 4];
        float4 a2 = *(const float4*)&As[(tr + 2) * LDP + k4 * 4];
        float4 a3 = *(const float4*)&As[(tr + 3) * LDP + k4 * 4];
        float4 b0 = *(const float4*)&Bs[(tg + 0) * LDP + k4 * 4];
        float4 b1 = *(const float4*)&Bs[(tg + 1) * LDP + k4 * 4];
        float4 b2 = *(const float4*)&Bs[(tg + 2) * LDP + k4 * 4];
        float4 b3 = *(const float4*)&Bs[(tg + 3) * LDP + k4 * 4];
        const float4 av[4] = {a0, a1, a2, a3};
        const float4 bv[4] = {b0, b1, b2, b3};
        #pragma unroll
        for (int i = 0; i < 4; i++)
            #pragma unroll
            for (int j = 0; j < 4; j++)
                acc[i][j] += av[i].x * bv[j].x + av[i].y * bv[j].y
                           + av[i].z * bv[j].z + av[i].w * bv[j].w;
    }
    float bias[4];
    #pragma unroll
    for (int j = 0; j < 4; j++) bias[j] = bih[g0 + tg + j] + bhh[g0 + tg + j];
    #pragma unroll
    for (int i = 0; i < 4; i++) {
        size_t row = (size_t)(r0 + tr + i) * G4 + g0 + tg;
        #pragma unroll
        for (int j = 0; j < 4; j++) gx[row + j] = acc[i][j] + bias[j];
    }
}

// gx2[t][g] = h1f[t][:] . Wih2[g][:] + biases; 256 thr, 2 gates.
__global__ void k_gx2(const float* h1f, const float* Wih,
                      const float* bih, const float* bhh, float* gx) {
    int t = blockIdx.x;
    __shared__ float xs[NH];
    int tid = threadIdx.x;
    int g0 = tid, g1 = tid + 256;
    if (tid < NH) xs[tid] = h1f[t * NH + tid];
    __syncthreads();
    float a0 = bih[g0] + bhh[g0];
    float a1 = bih[g1] + bhh[g1];
    #pragma unroll 4
    for (int k = 0; k < NH; k++) {
        a0 += Wih[(size_t)g0 * NH + k] * xs[k];
        a1 += Wih[(size_t)g1 * NH + k] * xs[k];
    }
    gx[(size_t)t * G4 + g0] = a0;
    gx[(size_t)t * G4 + g1] = a1;
}

// recurrence: 1 block/batch, 256 thr, 2 gates/thread. fp16 weights in VGPRs;
// R9: h read as 16 x ds_read_b128 (was 64 x b32) + fast expf/rcp gate math
// (libm tanhf was on the 200-step serial path).
template<int T, int NB>
__global__ __launch_bounds__(256, 1) void k_lstm(const float* gx, const float* Whh, float* hfinal) {
    int b = blockIdx.x;
    int t0 = threadIdx.x;
    int g0 = t0, g1 = t0 + 256;
    __shared__ __align__(16) _Float16 h2h[NH];
    __shared__ float gs[G4];
    h2v w0[NH / 2], w1[NH / 2];
    #pragma unroll
    for (int k = 0; k < NH; k += 4) {
        float4 a = *(const float4*)&Whh[(size_t)g0 * NH + k];
        w0[k / 2]     = h2v{(_Float16)a.x, (_Float16)a.y};
        w0[k / 2 + 1] = h2v{(_Float16)a.z, (_Float16)a.w};
        float4 c4 = *(const float4*)&Whh[(size_t)g1 * NH + k];
        w1[k / 2]     = h2v{(_Float16)c4.x, (_Float16)c4.y};
        w1[k / 2 + 1] = h2v{(_Float16)c4.z, (_Float16)c4.w};
    }
    if (t0 < NH) h2h[t0] = (_Float16)0.f;
    float c = 0.f, h = 0.f;
    float nx0 = gx[((size_t)0 * NB + b) * G4 + g0];
    float nx1 = gx[((size_t)0 * NB + b) * G4 + g1];
    __syncthreads();
    const h8v* hv8 = (const h8v*)h2h;
    for (int t = 0; t < T; t++) {
        float a0 = nx0, a1 = nx1;
        int tn = (t + 1 < T) ? (t + 1) : t;
        nx0 = gx[((size_t)tn * NB + b) * G4 + g0];          // prefetch next step
        nx1 = gx[((size_t)tn * NB + b) * G4 + g1];
        float p0 = 0.f, q0 = 0.f, p1 = 0.f, q1 = 0.f;
        #pragma unroll
        for (int m = 0; m < NH / 8; m++) {                  // 16 x b128 broadcast reads
            h8v h8 = hv8[m];
            h2v ha = __builtin_shufflevector(h8, h8, 0, 1);
            h2v hb = __builtin_shufflevector(h8, h8, 2, 3);
            h2v hc = __builtin_shufflevector(h8, h8, 4, 5);
            h2v hd = __builtin_shufflevector(h8, h8, 6, 7);
            p0 = FDOT2(w0[4 * m],     ha, p0);
            q0 = FDOT2(w0[4 * m + 1], hb, q0);
            p0 = FDOT2(w0[4 * m + 2], hc, p0);
            q0 = FDOT2(w0[4 * m + 3], hd, q0);
            p1 = FDOT2(w1[4 * m],     ha, p1);
            q1 = FDOT2(w1[4 * m + 1], hb, q1);
            p1 = FDOT2(w1[4 * m + 2], hc, p1);
            q1 = FDOT2(w1[4 * m + 3], hd, q1);
        }
        gs[g0] = a0 + p0 + q0;
        gs[g1] = a1 + p1 + q1;
        __syncthreads();
        if (t0 < NH) {
            int j = t0;
            float gi = gs[j], gf = gs[NH + j], gg = gs[2 * NH + j], go = gs[3 * NH + j];
            c = sigm_f(gf) * c + sigm_f(gi) * tanh_f(gg);
            h = sigm_f(go) * tanh_f(c);
            h2h[j] = (_Float16)h;
        }
        __syncthreads();
    }
    if (t0 < NH) hfinal[(size_t)b * NH + t0] = h;
}

// ============================ head ============================
// pass 1: 72 blocks (9 col-groups x 8 row-groups) x 64 lanes.
__global__ __launch_bounds__(64) void k_head1(const float* dvec, const float* m1w, float* colacc) {
    int rg = blockIdx.x & 7;           // 8 row groups x 144 rows
    int cg = blockIdx.x >> 3;          // 9 col groups x 64 cols
    int col = cg * 64 + threadIdx.x;
    int r0 = rg * 144;
    float acc = 0.f;
    #pragma unroll 4
    for (int i = r0; i < r0 + 144; i++)
        acc += dvec[i] * m1w[(size_t)i * 576 + col];
    atomicAdd(&colacc[col], acc);
}

// pass 2: out = sum_col (colacc+m1b)*m2w + m2b; dual-dtype store.
__global__ __launch_bounds__(256) void k_head2(const float* colacc, const float* m1b,
                                               const float* m2w, const float* m2b,
                                               unsigned int* out) {
    __shared__ float wr[4];
    int j = threadIdx.x;
    float sum = 0.f;
    for (int col = j; col < 576; col += 256)
        sum += (colacc[col] + m1b[col]) * m2w[col];
    #pragma unroll
    for (int off = 32; off > 0; off >>= 1) sum += __shfl_down(sum, off, 64);
    if ((j & 63) == 0) wr[j >> 6] = sum;
    __syncthreads();
    if (j == 0) {
        float s = wr[0] + wr[1] + wr[2] + wr[3] + m2b[0];
        bf16 hb = __float2bfloat16(s);
        unsigned short u;
        memcpy(&u, &hb, 2);
        out[0] = ((unsigned int)u << 16) | u;
    }
}

// ============================ launcher ============================

extern "C" void kernel_launch(void* const* d_in, const int* in_sizes, int n_in,
                              void* d_out, int out_size, void* d_ws, size_t ws_size,
                              hipStream_t stream) {
    const float* data0 = (const float*)d_in[0];
    const float* data1 = (const float*)d_in[1];
    const int*   ei    = (const int*)d_in[2];
    const float* W1    = (const float*)d_in[3];
    const float* b1    = (const float*)d_in[4];
    const float* W2    = (const float*)d_in[5];
    const float* b2    = (const float*)d_in[6];
    const float* Wih1  = (const float*)d_in[7];
    const float* Whh1  = (const float*)d_in[8];
    const float* bih1  = (const float*)d_in[9];
    const float* bhh1  = (const float*)d_in[10];
    const float* Wih2  = (const float*)d_in[11];
    const float* Whh2  = (const float*)d_in[12];
    const float* bih2  = (const float*)d_in[13];
    const float* bhh2  = (const float*)d_in[14];
    const float* m1w   = (const float*)d_in[15];
    const float* m1b   = (const float*)d_in[16];
    const float* m2w   = (const float*)d_in[17];
    const float* m2b   = (const float*)d_in[18];

    const int n = in_sizes[1] / NH;       // 100000
    const int E = in_sizes[2] / 2;        // 800000 (elements; int width sniffed on device)

    char* ws = (char*)d_ws;
    float* gx1   = (float*)(ws + OFF_GX1);
    float* gx2   = (float*)(ws + OFF_GX2);
    int*   deg   = (int*)  (ws + OFF_DEG);
    float* dinv  = (float*)(ws + OFF_DINV);
    int*   slot1 = (int*)  (ws + OFF_SL1);
    int*   slot2 = (int*)  (ws + OFF_SL2);
    int*   cnt   = (int*)  (ws + OFF_CNT);
    int2*  l1    = (int2*) (ws + OFF_L1);
    int*   s1l   = (int*)  (ws + OFF_S1);
    int2*  l2    = (int2*) (ws + OFF_L2);
    int*   s2l   = (int*)  (ws + OFF_S2);
    float* xw1   = (float*)(ws + OFF_XW1);
    float* h1    = (float*)(ws + OFF_H1);
    float* xw2   = (float*)(ws + OFF_XW2);
    float* dvec  = (float*)(ws + OFF_DVEC);
    float* h1f   = (float*)(ws + OFF_H1F);
    float* cacc  = (float*)(ws + OFF_CACC);

    // diagnostic canary (overwritten by k_head2 with the real answer)
    float v = 1.0f + (ws_size < WS_NEEDED ? 1.0f : 0.0f) + (n_in != 19 ? 2.0f : 0.0f);
    unsigned int fb; memcpy(&fb, &v, 4);
    unsigned int hi = fb >> 16;
    unsigned int canary_bits = (hi << 16) | hi;
    k_canary <<<1, 64, 0, stream>>>((unsigned int*)d_out, canary_bits);

    int nb = (n + 255) / 256;
    int eb = (E + 255) / 256;

    // subgraph build
    k_init   <<<nb, 256, 0, stream>>>(ei, deg, slot1, slot2, cnt, cacc, n);
    k_deg_l1 <<<eb, 256, 0, stream>>>(ei, E, deg, l1, cnt);
    k_dinv   <<<nb, 256, 0, stream>>>(deg, dinv, n);
    k_s1     <<<1, 256, 0, stream>>>(l1, cnt, slot1, s1l);
    k_s2self <<<8, 256, 0, stream>>>(s1l, cnt, slot2, s2l);
    k_l2     <<<eb, 256, 0, stream>>>(ei, E, slot1, l2, cnt, slot2, s2l);
    // GCN compute on active subgraph
    k_xw1    <<<S2CAP, NH, 0, stream>>>(data1, W1, s2l, cnt, xw1);
    k_h1init <<<S1CAP, NH, 0, stream>>>(xw1, s1l, cnt, slot2, dinv, h1);
    k_h1scat <<<LCAP2, NH, 0, stream>>>(xw1, l2, cnt, slot1, slot2, dinv, h1);
    k_xw2    <<<S1CAP, NH, 0, stream>>>(h1, W2, b1, cnt, xw2);
    k_gout   <<<NTGT, NH, 0, stream>>>(xw2, l1, cnt, slot1, dinv, b2, dvec);
    // LSTM path
    k_gx1    <<<800, 256, 0, stream>>>(data0, Wih1, bih1, bhh1, gx1);
    k_lstm<TSEQ, BBATCH><<<BBATCH, 256, 0, stream>>>(gx1, Whh1, h1f);
    k_gx2    <<<BBATCH, 256, 0, stream>>>(h1f, Wih2, bih2, bhh2, gx2);
    k_lstm<BBATCH, 1>  <<<1, 256, 0, stream>>>(gx2, Whh2, dvec + 1024);
    // head
    k_head1  <<<72, 64, 0, stream>>>(dvec, m1w, cacc);
    k_head2  <<<1, 256, 0, stream>>>(cacc, m1b, m2w, m2b, (unsigned int*)d_out);
    (void)out_size;
}

// Round 11
// 408.945 us; speedup vs baseline: 2.5923x; 1.0079x over previous
//
#include <hip/hip_runtime.h>
#include <hip/hip_bf16.h>
#include <cstring>

using bf16 = __hip_bfloat16;
typedef _Float16 h2v __attribute__((ext_vector_type(2)));
typedef _Float16 h8v __attribute__((ext_vector_type(8)));

#if __has_builtin(__builtin_amdgcn_fdot2)
__device__ __forceinline__ float FDOT2(h2v a, h2v b, float c) {
    return __builtin_amdgcn_fdot2(a, b, c, false);
}
#else
__device__ __forceinline__ float FDOT2(h2v a, h2v b, float c) {
    return c + (float)a.x * (float)b.x + (float)a.y * (float)b.y;
}
#endif

// fast sigmoid/tanh: v_exp_f32 + v_rcp_f32, saturate correctly at +-inf, no NaN.
__device__ __forceinline__ float sigm_f(float x) {
    return __builtin_amdgcn_rcpf(1.f + __expf(-x));
}
__device__ __forceinline__ float tanh_f(float x) {
    return 1.f - 2.f * __builtin_amdgcn_rcpf(1.f + __expf(2.f * x));
}

// ---- problem constants ----
constexpr int NH    = 128;    // hidden
constexpr int G4    = 512;    // 4*H gates
constexpr int TSEQ  = 200;
constexpr int BBATCH= 32;
constexpr int NTGT  = 8;

// ---- subgraph caps (Poisson means: |L1|~64, |S1|~72, |L2|~580, |S2|~650) ----
constexpr int LCAP1 = 1024;
constexpr int S1CAP = LCAP1 + NTGT;
constexpr int LCAP2 = 8192;
constexpr int S2CAP = LCAP2 + S1CAP;

// ---- workspace layout (bytes) ----
constexpr size_t algn(size_t x) { return (x + 255) & ~size_t(255); }
constexpr size_t OFF_GX1  = 0;                                            // 6400*512 f32
constexpr size_t OFF_GX2  = algn(OFF_GX1  + 6400ull * G4 * 4);            // 32*512 f32
constexpr size_t OFF_DEG  = algn(OFF_GX2  + 32ull * G4 * 4);              // N i32
constexpr size_t OFF_DINV = algn(OFF_DEG  + 100000ull * 4);               // (unused, kept)
constexpr size_t OFF_SL1  = algn(OFF_DINV + 100000ull * 4);               // N i32
constexpr size_t OFF_SL2  = algn(OFF_SL1  + 100000ull * 4);               // N i32
constexpr size_t OFF_CNT  = algn(OFF_SL2  + 100000ull * 4);               // 16 i32
constexpr size_t OFF_L1   = algn(OFF_CNT  + 64);                          // LCAP1 int2
constexpr size_t OFF_S1   = algn(OFF_L1   + (size_t)LCAP1 * 8);           // S1CAP i32
constexpr size_t OFF_L2   = algn(OFF_S1   + (size_t)S1CAP * 4);           // LCAP2 int2
constexpr size_t OFF_S2   = algn(OFF_L2   + (size_t)LCAP2 * 8);           // S2CAP i32
constexpr size_t OFF_XW1  = algn(OFF_S2   + (size_t)S2CAP * 4);           // S2CAP*128 f32
constexpr size_t OFF_H1   = algn(OFF_XW1  + (size_t)S2CAP * NH * 4);      // S1CAP*128 f32
constexpr size_t OFF_XW2  = algn(OFF_H1   + (size_t)S1CAP * NH * 4);      // S1CAP*128 f32
constexpr size_t OFF_DVEC = algn(OFF_XW2  + (size_t)S1CAP * NH * 4);      // 1152 f32
constexpr size_t OFF_H1F  = algn(OFF_DVEC + 1152ull * 4);                 // 32*128 f32
constexpr size_t OFF_CACC = algn(OFF_H1F  + 32ull * NH * 4);              // 576 f32
constexpr size_t WS_NEEDED = OFF_CACC + 576ull * 4;

// edge_index may be staged as int64 (reference dtype) or int32. If int64,
// odd int32 words are the (all-zero) high halves. cnt[15] = sniffed flag.
__device__ __forceinline__ int edge_at(const int* ei, int E, int is64, int row, int e) {
    return is64 ? ei[(((size_t)row * E) + e) * 2] : ei[((size_t)row * E) + e];
}

__device__ __forceinline__ float dinv_of(const int* deg, int v) {
    return rsqrtf((float)deg[v] + 1.0f);
}

// ============================ diagnostic canary ============================
__global__ void k_canary(unsigned int* out, unsigned int bits) {
    if (threadIdx.x == 0) out[0] = bits;
}

// ============================ GCN subgraph build ============================

__global__ void k_init(const int* ei, int* deg, int* slot1, int* slot2, int* cnt,
                       float* colacc, int n) {
    int i = blockIdx.x * 256 + threadIdx.x;
    if (i < 14) cnt[i] = 0;
    if (i == 15) cnt[15] = (ei[1] == 0 && ei[3] == 0 && ei[5] == 0 && ei[7] == 0) ? 1 : 0;
    if (i < 576) colacc[i] = 0.f;
    for (; i < n; i += gridDim.x * 256) { deg[i] = 0; slot1[i] = -1; slot2[i] = -1; }
}

__global__ void k_deg_l1(const int* ei, int E, int* deg, int2* l1, int* cnt) {
    int is64 = cnt[15];
    for (int e = blockIdx.x * 256 + threadIdx.x; e < E; e += gridDim.x * 256) {
        int d = edge_at(ei, E, is64, 1, e);
        if ((unsigned)d < 100000u) atomicAdd(&deg[d], 1);
        if (d <= 7000 && d >= 0 && d % 1000 == 0) {          // d in TARGET
            int s = edge_at(ei, E, is64, 0, e);
            int idx = atomicAdd(&cnt[0], 1);
            if (idx < LCAP1) l1[idx] = make_int2(s, d);
        }
    }
}

// S1 set build + S2 seeding (merged k_s1 + k_s2self; single block)
__global__ void k_s1(const int2* l1, int* cnt, int* slot1, int* s1list,
                     int* slot2, int* s2list) {
    __shared__ int ns1;
    if (threadIdx.x == 0) ns1 = 0;
    __syncthreads();
    int m = min(cnt[0], LCAP1);
    for (int i = threadIdx.x; i < NTGT + m; i += blockDim.x) {
        int v = (i < NTGT) ? i * 1000 : l1[i - NTGT].x;
        if ((unsigned)v >= 100000u) continue;
        int old = atomicCAS(&slot1[v], -1, -2);
        if (old == -1) {
            int idx = atomicAdd(&ns1, 1);
            if (idx < S1CAP) { s1list[idx] = v; atomicExch(&slot1[v], idx); }
        }
    }
    __syncthreads();
    int n1 = min(ns1, S1CAP);
    if (threadIdx.x == 0) cnt[1] = n1;
    for (int i = threadIdx.x; i < n1; i += blockDim.x) {
        int v = s1list[i];
        int old = atomicCAS(&slot2[v], -1, -2);
        if (old == -1) {
            int idx = atomicAdd(&cnt[2], 1);
            if (idx < S2CAP) { s2list[idx] = v; atomicExch(&slot2[v], idx); }
        }
    }
}

__global__ void k_l2(const int* ei, int E, const int* slot1,
                     int2* l2, int* cnt, int* slot2, int* s2list) {
    int is64 = cnt[15];
    for (int e = blockIdx.x * 256 + threadIdx.x; e < E; e += gridDim.x * 256) {
        int d = edge_at(ei, E, is64, 1, e);
        if ((unsigned)d >= 100000u) continue;
        if (slot1[d] >= 0) {
            int s = edge_at(ei, E, is64, 0, e);
            if ((unsigned)s >= 100000u) continue;
            int idx = atomicAdd(&cnt[3], 1);
            if (idx < LCAP2) l2[idx] = make_int2(s, d);
            int old = atomicCAS(&slot2[s], -1, -2);
            if (old == -1) {
                int j = atomicAdd(&cnt[2], 1);
                if (j < S2CAP) { s2list[j] = s; atomicExch(&slot2[s], j); }
            }
        }
    }
}

// ============================ GCN compute (fp32 inputs) ============================

__global__ void k_xw1(const float* x, const float* W, const int* s2list, const int* cnt, float* xw1) {
    int i = blockIdx.x;
    if (i >= min(cnt[2], S2CAP)) return;
    int node = s2list[i];
    __shared__ float xs[NH];
    int c = threadIdx.x;
    xs[c] = x[(size_t)node * NH + c];
    __syncthreads();
    float acc = 0.f;
    #pragma unroll 8
    for (int k = 0; k < NH; k++) acc += xs[k] * W[(size_t)k * NH + c];
    xw1[(size_t)i * NH + c] = acc;
}

__global__ void k_h1init(const float* xw1, const int* s1list, const int* cnt,
                         const int* slot2, const int* deg, float* h1) {
    int i = blockIdx.x;
    if (i >= min(cnt[1], S1CAP)) return;
    int node = s1list[i];
    int s2 = slot2[node];
    if (s2 < 0 || s2 >= S2CAP) s2 = 0;
    float v = dinv_of(deg, node);
    h1[i * NH + threadIdx.x] = xw1[(size_t)s2 * NH + threadIdx.x] * v * v;
}

__global__ void k_h1scat(const float* xw1, const int2* l2, const int* cnt,
                         const int* slot1, const int* slot2, const int* deg, float* h1) {
    int e = blockIdx.x;
    if (e >= min(cnt[3], LCAP2)) return;
    int2 sd = l2[e];
    int t1 = slot1[sd.y], s2 = slot2[sd.x];
    if (t1 < 0 || t1 >= S1CAP || s2 < 0 || s2 >= S2CAP) return;
    float w = dinv_of(deg, sd.x) * dinv_of(deg, sd.y);
    atomicAdd(&h1[t1 * NH + threadIdx.x],
              xw1[(size_t)s2 * NH + threadIdx.x] * w);
}

// fused: relu(h1 + b1) then @ W2
__global__ void k_xw2(const float* h1, const float* W, const float* b1, const int* cnt, float* xw2) {
    int i = blockIdx.x;
    if (i >= min(cnt[1], S1CAP)) return;
    __shared__ float xs[NH];
    int c = threadIdx.x;
    xs[c] = fmaxf(h1[i * NH + c] + b1[c], 0.f);
    __syncthreads();
    float acc = 0.f;
    #pragma unroll 8
    for (int k = 0; k < NH; k++) acc += xs[k] * W[(size_t)k * NH + c];
    xw2[(size_t)i * NH + c] = acc;
}

__global__ void k_gout(const float* xw2, const int2* l1, const int* cnt,
                       const int* slot1, const int* deg, const float* b2, float* dvec) {
    int t = blockIdx.x;             // 0..7
    int tgt = t * 1000;
    int c = threadIdx.x;
    float vt = dinv_of(deg, tgt);
    int st = slot1[tgt]; if (st < 0 || st >= S1CAP) st = 0;
    float acc = xw2[(size_t)st * NH + c] * vt * vt;
    int m = min(cnt[0], LCAP1);
    for (int e = 0; e < m; e++) {
        int2 sd = l1[e];
        if (sd.y == tgt) {
            int ss = slot1[sd.x];
            if (ss >= 0 && ss < S1CAP)
                acc += xw2[(size_t)ss * NH + c] * dinv_of(deg, sd.x) * vt;
        }
    }
    acc += b2[c];
    dvec[t * NH + c] = fmaxf(acc, 0.f);
}

// ============================ LSTM (fp32 inputs) ============================

// gx1 = data0_rows @ Wih1^T + bias, LDS-tiled GEMM (R8 fix for spill).
__global__ __launch_bounds__(256) void k_gx1(const float* data0, const float* Wih,
                                             const float* bih, const float* bhh, float* gx) {
    constexpr int LDP = 68;                       // pad 64->68 breaks bank conflicts
    __shared__ float As[64 * LDP];                // rows x k
    __shared__ float Bs[64 * LDP];                // gates x k
    int tid = threadIdx.x;
    int rb = blockIdx.x >> 3;                     // 0..99  row block
    int gb = blockIdx.x & 7;                      // 0..7   gate block
    int r0 = rb * 64, g0 = gb * 64;
    for (int i = tid; i < 64 * 64; i += 256) {
        int rr = i >> 6, k = i & 63;
        int r = r0 + rr, b = r & 31, t = r >> 5;
        As[rr * LDP + k] = data0[((size_t)b * TSEQ + t) * 64 + k];
        Bs[rr * LDP + k] = Wih[(size_t)(g0 + rr) * 64 + k];
    }
    __syncthreads();
    int tr = (tid & 15) * 4;                      // 4 rows
    int tg = (tid >> 4) * 4;                      // 4 gates
    float acc[4][4] = {};
    #pragma unroll
    for (int k4 = 0; k4 < 16; k4++) {
        float4 a0 = *(const float4*)&As[(tr + 0) * LDP + k4 * 4];
        float4 a1 = *(const float4*)&As[(tr + 1) * LDP + k4 * 4];
        float4 a2 = *(const float4*)&As[(tr + 2) * LDP + k4 * 4];
        float4 a3 = *(const float4*)&As[(tr + 3) * LDP + k4 * 4];
        float4 b0 = *(const float4*)&Bs[(tg + 0) * LDP + k4 * 4];
        float4 b1 = *(const float4*)&Bs[(tg + 1) * LDP + k4 * 4];
        float4 b2 = *(const float4*)&Bs[(tg + 2) * LDP + k4 * 4];
        float4 b3 = *(const float4*)&Bs[(tg + 3) * LDP + k4 * 4];
        const float4 av[4] = {a0, a1, a2, a3};
        const float4 bv[4] = {b0, b1, b2, b3};
        #pragma unroll
        for (int i = 0; i < 4; i++)
            #pragma unroll
            for (int j = 0; j < 4; j++)
                acc[i][j] += av[i].x * bv[j].x + av[i].y * bv[j].y
                           + av[i].z * bv[j].z + av[i].w * bv[j].w;
    }
    float bias[4];
    #pragma unroll
    for (int j = 0; j < 4; j++) bias[j] = bih[g0 + tg + j] + bhh[g0 + tg + j];
    #pragma unroll
    for (int i = 0; i < 4; i++) {
        size_t row = (size_t)(r0 + tr + i) * G4 + g0 + tg;
        #pragma unroll
        for (int j = 0; j < 4; j++) gx[row + j] = acc[i][j] + bias[j];
    }
}

// gx2[t][g] = h1f[t][:] . Wih2[g][:] + biases; 256 thr, 2 gates.
__global__ void k_gx2(const float* h1f, const float* Wih,
                      const float* bih, const float* bhh, float* gx) {
    int t = blockIdx.x;
    __shared__ float xs[NH];
    int tid = threadIdx.x;
    int g0 = tid, g1 = tid + 256;
    if (tid < NH) xs[tid] = h1f[t * NH + tid];
    __syncthreads();
    float a0 = bih[g0] + bhh[g0];
    float a1 = bih[g1] + bhh[g1];
    #pragma unroll 4
    for (int k = 0; k < NH; k++) {
        a0 += Wih[(size_t)g0 * NH + k] * xs[k];
        a1 += Wih[(size_t)g1 * NH + k] * xs[k];
    }
    gx[(size_t)t * G4 + g0] = a0;
    gx[(size_t)t * G4 + g1] = a1;
}

// R10 restructure: lane l of wave w handles unit j=w*32+(l&31); role l>>5:
//   role 0 computes gate rows (i, g), role 1 rows (f, o). The f/o results
//   cross to role 0 via __shfl_xor(32) — no gs LDS, 2 transc chains/thread.
// h double-buffered in LDS (write buf != read buf) -> ONE barrier per step
// (was 2 barriers + gs roundtrip + 4 serial transc on 128 threads = 1555 cyc).
template<int T, int NB>
__global__ __launch_bounds__(256, 1) void k_lstm(const float* gx, const float* Whh, float* hfinal) {
    int b = blockIdx.x;
    int tid = threadIdx.x;
    int w = tid >> 6, l = tid & 63;
    int j = w * 32 + (l & 31);                    // hidden unit
    int role = l >> 5;                            // 0: i,g   1: f,o
    int r0 = role ? (j + NH) : j;                 // f-row : i-row
    int r1 = role ? (j + 3 * NH) : (j + 2 * NH);  // o-row : g-row
    __shared__ __align__(16) _Float16 hbuf[2][NH];
    h2v w0[NH / 2], w1[NH / 2];
    #pragma unroll
    for (int k = 0; k < NH; k += 4) {
        float4 a = *(const float4*)&Whh[(size_t)r0 * NH + k];
        w0[k / 2]     = h2v{(_Float16)a.x, (_Float16)a.y};
        w0[k / 2 + 1] = h2v{(_Float16)a.z, (_Float16)a.w};
        float4 c4 = *(const float4*)&Whh[(size_t)r1 * NH + k];
        w1[k / 2]     = h2v{(_Float16)c4.x, (_Float16)c4.y};
        w1[k / 2 + 1] = h2v{(_Float16)c4.z, (_Float16)c4.w};
    }
    if (tid < NH) { hbuf[0][tid] = (_Float16)0.f; hbuf[1][tid] = (_Float16)0.f; }
    float c = 0.f, hout = 0.f;
    float nx0 = gx[((size_t)0 * NB + b) * G4 + r0];
    float nx1 = gx[((size_t)0 * NB + b) * G4 + r1];
    __syncthreads();
    for (int t = 0; t < T; t++) {
        const h8v* hv8 = (const h8v*)hbuf[t & 1];           // read prev-state buffer
        float a0 = nx0, a1 = nx1;
        int tn = (t + 1 < T) ? (t + 1) : t;
        nx0 = gx[((size_t)tn * NB + b) * G4 + r0];          // prefetch next step
        nx1 = gx[((size_t)tn * NB + b) * G4 + r1];
        float p0 = 0.f, q0 = 0.f, p1 = 0.f, q1 = 0.f;
        #pragma unroll
        for (int m = 0; m < NH / 8; m++) {                  // 16 b128 broadcast reads
            h8v h8 = hv8[m];
            h2v ha = __builtin_shufflevector(h8, h8, 0, 1);
            h2v hb = __builtin_shufflevector(h8, h8, 2, 3);
            h2v hc = __builtin_shufflevector(h8, h8, 4, 5);
            h2v hd = __builtin_shufflevector(h8, h8, 6, 7);
            p0 = FDOT2(w0[4 * m],     ha, p0);
            q0 = FDOT2(w0[4 * m + 1], hb, q0);
            p0 = FDOT2(w0[4 * m + 2], hc, p0);
            q0 = FDOT2(w0[4 * m + 3], hd, q0);
            p1 = FDOT2(w1[4 * m],     ha, p1);
            q1 = FDOT2(w1[4 * m + 1], hb, q1);
            p1 = FDOT2(w1[4 * m + 2], hc, p1);
            q1 = FDOT2(w1[4 * m + 3], hd, q1);
        }
        float ga = a0 + p0 + q0;                            // i-pre or f-pre
        float gb = a1 + p1 + q1;                            // g-pre or o-pre
        float s  = sigm_f(ga);                              // sigm(i) | sigm(f)
        float tg = role ? sigm_f(gb) : tanh_f(gb);          // tanh(g) | sigm(o)
        float u  = s * tg;                                  // role0: sigm(i)*tanh(g)
        float fv = __shfl_xor(s,  32);                      // role0 gets sigm(f)
        float ov = __shfl_xor(tg, 32);                      // role0 gets sigm(o)
        if (role == 0) {
            c = fv * c + u;
            hout = ov * tanh_f(c);
            hbuf[(t + 1) & 1][j] = (_Float16)hout;          // write other buffer
        }
        __syncthreads();                                    // single barrier/step
    }
    if (role == 0) hfinal[(size_t)b * NH + j] = hout;
}

// ============================ head ============================
// pass 1: 72 blocks (9 col-groups x 8 row-groups) x 64 lanes.
__global__ __launch_bounds__(64) void k_head1(const float* dvec, const float* m1w, float* colacc) {
    int rg = blockIdx.x & 7;           // 8 row groups x 144 rows
    int cg = blockIdx.x >> 3;          // 9 col groups x 64 cols
    int col = cg * 64 + threadIdx.x;
    int r0 = rg * 144;
    float acc = 0.f;
    #pragma unroll 4
    for (int i = r0; i < r0 + 144; i++)
        acc += dvec[i] * m1w[(size_t)i * 576 + col];
    atomicAdd(&colacc[col], acc);
}

// pass 2: out = sum_col (colacc+m1b)*m2w + m2b; dual-dtype store.
__global__ __launch_bounds__(256) void k_head2(const float* colacc, const float* m1b,
                                               const float* m2w, const float* m2b,
                                               unsigned int* out) {
    __shared__ float wr[4];
    int j = threadIdx.x;
    float sum = 0.f;
    for (int col = j; col < 576; col += 256)
        sum += (colacc[col] + m1b[col]) * m2w[col];
    #pragma unroll
    for (int off = 32; off > 0; off >>= 1) sum += __shfl_down(sum, off, 64);
    if ((j & 63) == 0) wr[j >> 6] = sum;
    __syncthreads();
    if (j == 0) {
        float s = wr[0] + wr[1] + wr[2] + wr[3] + m2b[0];
        bf16 hb = __float2bfloat16(s);
        unsigned short u;
        memcpy(&u, &hb, 2);
        out[0] = ((unsigned int)u << 16) | u;
    }
}

// ============================ launcher ============================

extern "C" void kernel_launch(void* const* d_in, const int* in_sizes, int n_in,
                              void* d_out, int out_size, void* d_ws, size_t ws_size,
                              hipStream_t stream) {
    const float* data0 = (const float*)d_in[0];
    const float* data1 = (const float*)d_in[1];
    const int*   ei    = (const int*)d_in[2];
    const float* W1    = (const float*)d_in[3];
    const float* b1    = (const float*)d_in[4];
    const float* W2    = (const float*)d_in[5];
    const float* b2    = (const float*)d_in[6];
    const float* Wih1  = (const float*)d_in[7];
    const float* Whh1  = (const float*)d_in[8];
    const float* bih1  = (const float*)d_in[9];
    const float* bhh1  = (const float*)d_in[10];
    const float* Wih2  = (const float*)d_in[11];
    const float* Whh2  = (const float*)d_in[12];
    const float* bih2  = (const float*)d_in[13];
    const float* bhh2  = (const float*)d_in[14];
    const float* m1w   = (const float*)d_in[15];
    const float* m1b   = (const float*)d_in[16];
    const float* m2w   = (const float*)d_in[17];
    const float* m2b   = (const float*)d_in[18];

    const int n = in_sizes[1] / NH;       // 100000
    const int E = in_sizes[2] / 2;        // 800000 (elements; int width sniffed on device)

    char* ws = (char*)d_ws;
    float* gx1   = (float*)(ws + OFF_GX1);
    float* gx2   = (float*)(ws + OFF_GX2);
    int*   deg   = (int*)  (ws + OFF_DEG);
    int*   slot1 = (int*)  (ws + OFF_SL1);
    int*   slot2 = (int*)  (ws + OFF_SL2);
    int*   cnt   = (int*)  (ws + OFF_CNT);
    int2*  l1    = (int2*) (ws + OFF_L1);
    int*   s1l   = (int*)  (ws + OFF_S1);
    int2*  l2    = (int2*) (ws + OFF_L2);
    int*   s2l   = (int*)  (ws + OFF_S2);
    float* xw1   = (float*)(ws + OFF_XW1);
    float* h1    = (float*)(ws + OFF_H1);
    float* xw2   = (float*)(ws + OFF_XW2);
    float* dvec  = (float*)(ws + OFF_DVEC);
    float* h1f   = (float*)(ws + OFF_H1F);
    float* cacc  = (float*)(ws + OFF_CACC);

    // diagnostic canary (overwritten by k_head2 with the real answer)
    float v = 1.0f + (ws_size < WS_NEEDED ? 1.0f : 0.0f) + (n_in != 19 ? 2.0f : 0.0f);
    unsigned int fb; memcpy(&fb, &v, 4);
    unsigned int hi = fb >> 16;
    unsigned int canary_bits = (hi << 16) | hi;
    k_canary <<<1, 64, 0, stream>>>((unsigned int*)d_out, canary_bits);

    int nb = (n + 255) / 256;
    int eb = (E + 255) / 256;

    // subgraph build
    k_init   <<<nb, 256, 0, stream>>>(ei, deg, slot1, slot2, cnt, cacc, n);
    k_deg_l1 <<<eb, 256, 0, stream>>>(ei, E, deg, l1, cnt);
    k_s1     <<<1, 256, 0, stream>>>(l1, cnt, slot1, s1l, slot2, s2l);
    k_l2     <<<eb, 256, 0, stream>>>(ei, E, slot1, l2, cnt, slot2, s2l);
    // GCN compute on active subgraph
    k_xw1    <<<S2CAP, NH, 0, stream>>>(data1, W1, s2l, cnt, xw1);
    k_h1init <<<S1CAP, NH, 0, stream>>>(xw1, s1l, cnt, slot2, deg, h1);
    k_h1scat <<<LCAP2, NH, 0, stream>>>(xw1, l2, cnt, slot1, slot2, deg, h1);
    k_xw2    <<<S1CAP, NH, 0, stream>>>(h1, W2, b1, cnt, xw2);
    k_gout   <<<NTGT, NH, 0, stream>>>(xw2, l1, cnt, slot1, deg, b2, dvec);
    // LSTM path
    k_gx1    <<<800, 256, 0, stream>>>(data0, Wih1, bih1, bhh1, gx1);
    k_lstm<TSEQ, BBATCH><<<BBATCH, 256, 0, stream>>>(gx1, Whh1, h1f);
    k_gx2    <<<BBATCH, 256, 0, stream>>>(h1f, Wih2, bih2, bhh2, gx2);
    k_lstm<BBATCH, 1>  <<<1, 256, 0, stream>>>(gx2, Whh2, dvec + 1024);
    // head
    k_head1  <<<72, 64, 0, stream>>>(dvec, m1w, cacc);
    k_head2  <<<1, 256, 0, stream>>>(cacc, m1b, m2w, m2b, (unsigned int*)d_out);
    (void)out_size;
}